// Round 7
// baseline (306.770 us; speedup 1.0000x reference)
//
#include <hip/hip_runtime.h>
#include <hip/hip_bf16.h>

// GaussianPolicy: SNN-LIF frontend + 2-branch MLP heads.
// B=4096, IN=512, H=2048, A=32. fp32 in/out; fp16 MFMA compute internally.
// Trunk GEMMs: 256x256 tile, BK=64, 8 waves, XOR-swizzled LDS (T2),
// counted vmcnt pipeline (T3/T4), setprio (T5).
// LIF: same schedule class, 128x128 tile, BK=128 (32 MFMA/wave/iter),
// 5 s-slices sequential with per-thread (mem,cnt) LIF state.

typedef _Float16 f16;
using f32x4 = __attribute__((ext_vector_type(4))) float;
using f16x8 = __attribute__((ext_vector_type(8))) f16;   // 8 fp16 = 4 VGPRs

#define MFMA16(a, b, c) __builtin_amdgcn_mfma_f32_16x16x32_f16((a), (b), (c), 0, 0, 0)
#define VMW8()  asm volatile("s_waitcnt vmcnt(8)" ::: "memory")
#define VMW4()  asm volatile("s_waitcnt vmcnt(4)" ::: "memory")
#define VMW0()  asm volatile("s_waitcnt vmcnt(0)" ::: "memory")
#define LGKM0() asm volatile("s_waitcnt lgkmcnt(0)" ::: "memory")
#define BARRIER() __builtin_amdgcn_s_barrier()
#define SCHED0() __builtin_amdgcn_sched_barrier(0)

__device__ __forceinline__ void gload16(const void* g, void* l) {
  // async global->LDS, 16B/lane; LDS dest must be wave-uniform base + lane*16
  __builtin_amdgcn_global_load_lds(
      (const __attribute__((address_space(1))) unsigned int*)g,
      (__attribute__((address_space(3))) unsigned int*)l, 16, 0, 0);
}

// ---------------------------------------------------------------------------
// fp32 -> fp16 convert, 8 elems/thread
// ---------------------------------------------------------------------------
__global__ __launch_bounds__(256) void cvt_kernel(
    const float* __restrict__ src, f16* __restrict__ dst, int n8)
{
  int i = blockIdx.x * 256 + threadIdx.x;
  if (i >= n8) return;
  const float4* s4 = (const float4*)src;
  float4 a = s4[(size_t)i * 2], b = s4[(size_t)i * 2 + 1];
  f16x8 d;
  d[0] = (f16)a.x; d[1] = (f16)a.y; d[2] = (f16)a.z; d[3] = (f16)a.w;
  d[4] = (f16)b.x; d[5] = (f16)b.y; d[6] = (f16)b.z; d[7] = (f16)b.w;
  *(f16x8*)(dst + (size_t)i * 8) = d;
}

// two equal-size tensors in one dispatch (saves a launch)
__global__ __launch_bounds__(256) void cvt2_kernel(
    const float* __restrict__ s0, const float* __restrict__ s1,
    f16* __restrict__ d0, f16* __restrict__ d1, int n8each)
{
  int i = blockIdx.x * 256 + threadIdx.x;
  const float* src = (i < n8each) ? s0 : s1;
  f16* dst = (i < n8each) ? d0 : d1;
  int k = (i < n8each) ? i : i - n8each;
  if (k >= n8each) return;
  const float4* s4 = (const float4*)src;
  float4 a = s4[(size_t)k * 2], b = s4[(size_t)k * 2 + 1];
  f16x8 d;
  d[0] = (f16)a.x; d[1] = (f16)a.y; d[2] = (f16)a.z; d[3] = (f16)a.w;
  d[4] = (f16)b.x; d[5] = (f16)b.y; d[6] = (f16)b.z; d[7] = (f16)b.w;
  *(f16x8*)(dst + (size_t)k * 8) = d;
}

// ---------------------------------------------------------------------------
// LIF kernel, trunk256-class schedule. Tile 128(M=batch) x 128(N=hidden),
// BK=128 (two K-tiles per s-slice... K=512 -> 4 per slice, 20 total),
// 8 waves (2Mx4N), wave 64x32 = 4x2 frags x 4 k-chunks = 32 MFMA/iter.
// Per-thread LIF state (mem,cnt); slice boundary every 4th iter.
// LDS: A,B 2 slots each [128][128] f16 XOR-swizzled = 128 KB.
// ---------------------------------------------------------------------------
__global__ __launch_bounds__(512, 1) void lif256_kernel(
    const f16* __restrict__ S,    // [4096*5, 512] fp16 (row (b*5+s))
    const f16* __restrict__ W,    // [2048, 512] fp16
    const float* __restrict__ bl, // [2048] fp32
    f16* __restrict__ X)          // [4096, 2048] fp16
{
  __shared__ alignas(16) f16 lds[4][128 * 128];  // [0,1]=A slots, [2,3]=B slots

  const int tid = threadIdx.x, wid = tid >> 6, lane = tid & 63;
  // XCD swizzle (nwg=512): consecutive wg -> same XCD; bn fastest.
  const int wg = ((int)blockIdx.x % 8) * 64 + (int)blockIdx.x / 8;
  const int bn = wg & 15, bm = wg >> 4;          // nbn=16, nbm=32
  const int b0 = bm * 128, h0 = bn * 128;
  const int wr0 = (wid >> 2) * 64, wc0 = (wid & 3) * 32;
  const int fr = lane & 15, fq = lane >> 4;
  const int sr = tid >> 4, scb = (tid & 15) * 16; // staging row-in-32, col byte

  f32x4 acc[4][2] = {};
  float mem[4][2][4] = {};
  float cnt[4][2][4] = {};

  // stage one K-tile: A 4 gloads + B 4 gloads (each 32 rows x 256B)
  auto STAGE = [&](int slot, int g) {
    const int s = g >> 2, k0 = (g & 3) * 128;
#pragma unroll
    for (int l = 0; l < 4; ++l) {
      const int row = l * 32 + sr;
      const int c2 = scb ^ ((row & 7) << 4);      // pre-swizzled source col (bytes)
      gload16(S + ((size_t)(b0 + row) * 5 + s) * 512 + k0 + (c2 >> 1),
              &lds[slot][l * 4096 + tid * 8]);
    }
#pragma unroll
    for (int l = 0; l < 4; ++l) {
      const int row = l * 32 + sr;
      const int c2 = scb ^ ((row & 7) << 4);
      gload16(W + (size_t)(h0 + row) * 512 + k0 + (c2 >> 1),
              &lds[2 + slot][l * 4096 + tid * 8]);
    }
  };

  auto LDA_ = [&](int slot, int mf, int ks) -> f16x8 {
    const int row = wr0 + mf * 16 + fr;
    const int c = (ks * 64 + fq * 16) ^ ((row & 7) << 4);
    return *(const f16x8*)&lds[slot][row * 128 + (c >> 1)];
  };
  auto LDB_ = [&](int slot, int nf, int ks) -> f16x8 {
    const int row = wc0 + nf * 16 + fr;
    const int c = (ks * 64 + fq * 16) ^ ((row & 7) << 4);
    return *(const f16x8*)&lds[2 + slot][row * 128 + (c >> 1)];
  };

  const float bias[2] = { bl[h0 + wc0 + fr], bl[h0 + wc0 + 16 + fr] };

  STAGE(0, 0);
  STAGE(1, 1);
  VMW8();          // tile 0 landed; tile 1's 8 loads stay in flight
  BARRIER();
  SCHED0();

#pragma unroll 4
  for (int kt = 0; kt < 20; ++kt) {
    const int slot = kt & 1;   // compile-time under unroll-4

    f16x8 b[2][4];
#pragma unroll
    for (int nf = 0; nf < 2; ++nf)
#pragma unroll
      for (int ks = 0; ks < 4; ++ks)
        b[nf][ks] = LDB_(slot, nf, ks);

    f16x8 a0[4][2], a1[4][2];
#pragma unroll
    for (int mf = 0; mf < 4; ++mf) {
      a0[mf][0] = LDA_(slot, mf, 0);
      a0[mf][1] = LDA_(slot, mf, 1);
    }
#pragma unroll
    for (int mf = 0; mf < 4; ++mf) {
      a1[mf][0] = LDA_(slot, mf, 2);
      a1[mf][1] = LDA_(slot, mf, 3);
    }

    __builtin_amdgcn_s_setprio(1);
#pragma unroll
    for (int mf = 0; mf < 4; ++mf)
#pragma unroll
      for (int nf = 0; nf < 2; ++nf) {
        acc[mf][nf] = MFMA16(a0[mf][0], b[nf][0], acc[mf][nf]);
        acc[mf][nf] = MFMA16(a0[mf][1], b[nf][1], acc[mf][nf]);
      }
#pragma unroll
    for (int mf = 0; mf < 4; ++mf)
#pragma unroll
      for (int nf = 0; nf < 2; ++nf) {
        acc[mf][nf] = MFMA16(a1[mf][0], b[nf][2], acc[mf][nf]);
        acc[mf][nf] = MFMA16(a1[mf][1], b[nf][3], acc[mf][nf]);
      }
    __builtin_amdgcn_s_setprio(0);

    if ((kt & 3) == 3) {
      // slice boundary: 3 LIF reps with fc = acc + bias; reset acc
#pragma unroll
      for (int mf = 0; mf < 4; ++mf)
#pragma unroll
        for (int nf = 0; nf < 2; ++nf) {
#pragma unroll
          for (int r = 0; r < 4; ++r) {
            const float fc = acc[mf][nf][r] + bias[nf];
            float m = mem[mf][nf][r], c = cnt[mf][nf][r];
#pragma unroll
            for (int j = 0; j < 3; ++j) {
              m = ((m > 0.2f) ? 0.f : m * 0.2f) + fc;   // DECAY=0.2, spike resets
              c += (m > 0.2f) ? 1.f : 0.f;              // THRESH=0.2
            }
            mem[mf][nf][r] = m; cnt[mf][nf][r] = c;
          }
          acc[mf][nf] = f32x4{0.f, 0.f, 0.f, 0.f};
        }
    }

    LGKM0();        // all reads of this slot complete
    BARRIER();      // ... in every wave
    SCHED0();
    if (kt + 2 < 20) {
      STAGE(slot, kt + 2);   // overwrite now-dead slot; stays in flight
      SCHED0();
      VMW8();                // tile kt+1 landed (kt+2's 8 still flying)
    } else if (kt + 1 < 20) {
      VMW0();                // tail
    }
    BARRIER();
    SCHED0();
  }

#pragma unroll
  for (int nf = 0; nf < 2; ++nf) {
    const int col = h0 + wc0 + nf * 16 + fr;
#pragma unroll
    for (int mf = 0; mf < 4; ++mf) {
      const int row0 = b0 + wr0 + mf * 16 + fq * 4;
#pragma unroll
      for (int r = 0; r < 4; ++r)
        X[(size_t)(row0 + r) * 2048 + col] = (f16)(cnt[mf][nf][r] / 15.0f);
    }
  }
}

// ---------------------------------------------------------------------------
// Trunk GEMM: C = relu(A @ W^T + bias), fp16 in/out, fp32 bias/accum.
// 256x256 tile, BK=64, 8 waves (2Mx4N), wave output 128x64 = 8x4 frags.
// (unchanged — proven round 5)
// ---------------------------------------------------------------------------
__global__ __launch_bounds__(512, 2) void trunk256_kernel(
    const f16* __restrict__ A0, const f16* __restrict__ A1, int lda,
    const f16* __restrict__ W0, const f16* __restrict__ W1,
    const float* __restrict__ bb0, const float* __restrict__ bb1,
    f16* __restrict__ C0, f16* __restrict__ C1, int ldc,
    int nbm, int nbn_half, int K)
{
  __shared__ alignas(16) f16 lds[4][256 * 64];   // [0,1]=A slots, [2,3]=B slots

  const int tid = threadIdx.x, wid = tid >> 6, lane = tid & 63;
  const int nwg = nbm * nbn_half * 2, q8 = nwg / 8;
  const int wg = ((int)blockIdx.x % 8) * q8 + (int)blockIdx.x / 8;
  const int bmi = wg % nbm, t = wg / nbm;
  const int half = (t >= nbn_half);
  const f16* Ap = half ? A1 : A0;
  const f16* Wp = half ? W1 : W0;
  const float* bias = half ? bb1 : bb0;
  f16* C = half ? C1 : C0;
  const int bm0 = bmi * 256;
  const int bn0 = (half ? t - nbn_half : t) * 256;

  const int wr0 = (wid >> 2) * 128, wc0 = (wid & 3) * 64;
  const int fr = lane & 15, fq = lane >> 4;
  const int sr = tid >> 3, scb = (tid & 7) * 16;

  f32x4 acc[8][4] = {};
  const int NT = K / 64;

  auto STAGE = [&](int slot, int kt) {
    const int k0 = kt * 64;
#pragma unroll
    for (int l = 0; l < 4; ++l) {
      const int row = l * 64 + sr;
      const int c2 = scb ^ ((row & 7) << 4);
      gload16(Ap + (size_t)(bm0 + row) * lda + k0 + (c2 >> 1),
              &lds[slot][l * 4096 + tid * 8]);
    }
#pragma unroll
    for (int l = 0; l < 4; ++l) {
      const int row = l * 64 + sr;
      const int c2 = scb ^ ((row & 7) << 4);
      gload16(Wp + (size_t)(bn0 + row) * K + k0 + (c2 >> 1),
              &lds[2 + slot][l * 4096 + tid * 8]);
    }
  };

  auto LDA_ = [&](int slot, int mf, int ks) -> f16x8 {
    const int row = wr0 + mf * 16 + fr;
    const int c = (ks * 64 + fq * 16) ^ ((row & 7) << 4);
    return *(const f16x8*)&lds[slot][row * 64 + (c >> 1)];
  };
  auto LDB_ = [&](int slot, int nf, int ks) -> f16x8 {
    const int row = wc0 + nf * 16 + fr;
    const int c = (ks * 64 + fq * 16) ^ ((row & 7) << 4);
    return *(const f16x8*)&lds[2 + slot][row * 64 + (c >> 1)];
  };

  STAGE(0, 0);
  STAGE(1, 1);
  VMW8();          // tile 0 landed; tile 1's 8 loads stay in flight
  BARRIER();
  SCHED0();

  for (int kt = 0; kt < NT; ++kt) {
    const int slot = kt & 1;

    f16x8 b[4][2];
#pragma unroll
    for (int nf = 0; nf < 4; ++nf) {
      b[nf][0] = LDB_(slot, nf, 0);
      b[nf][1] = LDB_(slot, nf, 1);
    }
    f16x8 a0[2][2], a1[2][2];
#pragma unroll
    for (int i = 0; i < 2; ++i) {
      a0[i][0] = LDA_(slot, i, 0);
      a0[i][1] = LDA_(slot, i, 1);
    }

    auto QUAD = [&](int mbase, f16x8 (&a)[2][2]) {
      __builtin_amdgcn_s_setprio(1);
#pragma unroll
      for (int nf = 0; nf < 4; ++nf) {
        acc[mbase][nf]     = MFMA16(a[0][0], b[nf][0], acc[mbase][nf]);
        acc[mbase][nf]     = MFMA16(a[0][1], b[nf][1], acc[mbase][nf]);
        acc[mbase + 1][nf] = MFMA16(a[1][0], b[nf][0], acc[mbase + 1][nf]);
        acc[mbase + 1][nf] = MFMA16(a[1][1], b[nf][1], acc[mbase + 1][nf]);
      }
      __builtin_amdgcn_s_setprio(0);
    };

#pragma unroll
    for (int i = 0; i < 2; ++i) { a1[i][0] = LDA_(slot, 2 + i, 0); a1[i][1] = LDA_(slot, 2 + i, 1); }
    QUAD(0, a0);
#pragma unroll
    for (int i = 0; i < 2; ++i) { a0[i][0] = LDA_(slot, 4 + i, 0); a0[i][1] = LDA_(slot, 4 + i, 1); }
    QUAD(2, a1);
#pragma unroll
    for (int i = 0; i < 2; ++i) { a1[i][0] = LDA_(slot, 6 + i, 0); a1[i][1] = LDA_(slot, 6 + i, 1); }
    QUAD(4, a0);
    QUAD(6, a1);

    LGKM0();
    BARRIER();
    SCHED0();
    if (kt + 2 < NT) {
      STAGE(slot, kt + 2);
      SCHED0();
      VMW8();
    } else if (kt + 1 < NT) {
      VMW0();
    }
    BARRIER();
    SCHED0();
  }

#pragma unroll
  for (int nf = 0; nf < 4; ++nf) {
    const int col = bn0 + wc0 + nf * 16 + fr;
    const float bv = bias[col];
#pragma unroll
    for (int m = 0; m < 8; ++m) {
      const int row0 = bm0 + wr0 + m * 16 + fq * 4;
#pragma unroll
      for (int r = 0; r < 4; ++r) {
        float v = fmaxf(acc[m][nf][r] + bv, 0.f);
        C[(size_t)(row0 + r) * ldc + col] = (f16)v;
      }
    }
  }
}

// ---------------------------------------------------------------------------
// Heads: mean = h12@Wm^T + bm ; log_std = clip(h22@Wls^T + bls, -20, 2). fp32 out.
// ---------------------------------------------------------------------------
__global__ __launch_bounds__(256) void head_kernel(
    const f16* __restrict__ H1, const f16* __restrict__ H2,
    const f16* __restrict__ Wm, const float* __restrict__ bm,
    const f16* __restrict__ Wls, const float* __restrict__ bls,
    float* __restrict__ OUT, int M, int K)
{
  const int tid = threadIdx.x, wid = tid >> 6, lane = tid & 63;
  const int m0 = blockIdx.x * 64 + wid * 16;
  const int kb = (lane >> 4) * 8, fr = lane & 15, fq = lane >> 4;

  f32x4 a1[2] = {}, a2[2] = {};
  for (int k0 = 0; k0 < K; k0 += 32) {
    f16x8 f1 = *(const f16x8*)&H1[(size_t)(m0 + fr) * K + k0 + kb];
    f16x8 f2 = *(const f16x8*)&H2[(size_t)(m0 + fr) * K + k0 + kb];
#pragma unroll
    for (int n = 0; n < 2; ++n) {
      f16x8 wm = *(const f16x8*)&Wm[(size_t)(n * 16 + fr) * K + k0 + kb];
      f16x8 wl = *(const f16x8*)&Wls[(size_t)(n * 16 + fr) * K + k0 + kb];
      a1[n] = MFMA16(f1, wm, a1[n]);
      a2[n] = MFMA16(f2, wl, a2[n]);
    }
  }

#pragma unroll
  for (int n = 0; n < 2; ++n) {
    const int col = n * 16 + fr;
    const float bvm = bm[col];
    const float bvl = bls[col];
#pragma unroll
    for (int r = 0; r < 4; ++r) {
      const int row = m0 + fq * 4 + r;
      OUT[(size_t)row * 32 + col] = a1[n][r] + bvm;
      float lv = a2[n][r] + bvl;
      OUT[(size_t)M * 32 + (size_t)row * 32 + col] = fminf(fmaxf(lv, -20.f), 2.f);
    }
  }
}

// ---------------------------------------------------------------------------
extern "C" void kernel_launch(void* const* d_in, const int* in_sizes, int n_in,
                              void* d_out, int out_size, void* d_ws, size_t ws_size,
                              hipStream_t stream) {
  const float* state = (const float*)d_in[0];
  const float* W_lif = (const float*)d_in[1];
  const float* b_lif = (const float*)d_in[2];
  const float* W11   = (const float*)d_in[3];
  const float* b11   = (const float*)d_in[4];
  const float* W12   = (const float*)d_in[5];
  const float* b12   = (const float*)d_in[6];
  const float* W21   = (const float*)d_in[7];
  const float* b21   = (const float*)d_in[8];
  const float* W22   = (const float*)d_in[9];
  const float* b22   = (const float*)d_in[10];
  const float* Wm    = (const float*)d_in[11];
  const float* bm    = (const float*)d_in[12];
  const float* Wls   = (const float*)d_in[13];
  const float* bls   = (const float*)d_in[14];
  float* out = (float*)d_out;

  const int B = 4096, IN = 512, H = 2048;
  char* ws = (char*)d_ws;
  // layout (bytes), peak 80.0 MB:
  f16* x    = (f16*)(ws);
  f16* h1   = (f16*)(ws + 16777216);
  f16* h2   = (f16*)(ws + 33554432);
  f16* s16  = (f16*)(ws + 50331648);
  f16* wl16 = (f16*)(ws + 71303168);
  f16* w11h = (f16*)(ws + 50331648);
  f16* w21h = (f16*)(ws + 58720256);
  f16* h22  = (f16*)(ws + 50331648);
  f16* w12h = (f16*)(ws + 67108864);
  f16* w22h = (f16*)(ws + 75497472);
  f16* wmh  = (f16*)(ws + 67108864);
  f16* wlsh = (f16*)(ws + 67239936);
  f16* h12  = x;

  // 1) converts for LIF
  cvt_kernel<<<(B * 5 * IN / 8) / 256, 256, 0, stream>>>(state, s16, B * 5 * IN / 8);
  cvt_kernel<<<(H * IN / 8) / 256, 256, 0, stream>>>(W_lif, wl16, H * IN / 8);

  // 2) fused fc-GEMM + LIF -> x  (trunk256-class schedule, BK=128)
  lif256_kernel<<<512, 512, 0, stream>>>(s16, wl16, b_lif, x);

  // 3) layer-1: cvt W11+W21 (over s16), fused 256^2 GEMM -> h1, h2
  cvt2_kernel<<<2 * (H * H / 8) / 256, 256, 0, stream>>>(W11, W21, w11h, w21h, H * H / 8);
  trunk256_kernel<<<256, 512, 0, stream>>>(x, x, H, w11h, w21h, b11, b21,
                                           h1, h2, H, 16, 8, H);

  // 4) layer-2: cvt W12+W22, fused 256^2 GEMM -> h12 (over x), h22
  cvt2_kernel<<<2 * (H * H / 8) / 256, 256, 0, stream>>>(W12, W22, w12h, w22h, H * H / 8);
  trunk256_kernel<<<256, 512, 0, stream>>>(h1, h2, H, w12h, w22h, b12, b22,
                                           h12, h22, H, 16, 8, H);

  // 5) heads -> d_out = [mean | log_std] fp32
  cvt2_kernel<<<2 * (32 * H / 8) / 256, 256, 0, stream>>>(Wm, Wls, wmh, wlsh, 32 * H / 8);
  head_kernel<<<B / 64, 256, 0, stream>>>(h12, h22, wmh, bm, wlsh, bls, out, B, H);
}

// Round 8
// 290.595 us; speedup vs baseline: 1.0557x; 1.0557x over previous
//
#include <hip/hip_runtime.h>
#include <hip/hip_bf16.h>

// GaussianPolicy: SNN-LIF frontend + 2-branch MLP heads.
// B=4096, IN=512, H=2048, A=32. fp32 in/out; fp16 MFMA compute internally.
// Both GEMM kernels: XOR-swizzled LDS (T2), fine phase-split with 2 barriers
// per phase (T3), counted vmcnt never drained mid-loop (T4), setprio (T5).

typedef _Float16 f16;
using f32x4 = __attribute__((ext_vector_type(4))) float;
using f16x8 = __attribute__((ext_vector_type(8))) f16;   // 8 fp16 = 4 VGPRs

#define MFMA16(a, b, c) __builtin_amdgcn_mfma_f32_16x16x32_f16((a), (b), (c), 0, 0, 0)
#define VMW8()  asm volatile("s_waitcnt vmcnt(8)" ::: "memory")
#define VMW4()  asm volatile("s_waitcnt vmcnt(4)" ::: "memory")
#define VMW0()  asm volatile("s_waitcnt vmcnt(0)" ::: "memory")
#define LGKM0() asm volatile("s_waitcnt lgkmcnt(0)" ::: "memory")
#define BARRIER() __builtin_amdgcn_s_barrier()
#define SCHED0() __builtin_amdgcn_sched_barrier(0)

__device__ __forceinline__ void gload16(const void* g, void* l) {
  // async global->LDS, 16B/lane; LDS dest = wave-uniform base + lane*16
  __builtin_amdgcn_global_load_lds(
      (const __attribute__((address_space(1))) unsigned int*)g,
      (__attribute__((address_space(3))) unsigned int*)l, 16, 0, 0);
}

// ---------------------------------------------------------------------------
// fp32 -> fp16 convert, 8 elems/thread
// ---------------------------------------------------------------------------
__global__ __launch_bounds__(256) void cvt_kernel(
    const float* __restrict__ src, f16* __restrict__ dst, int n8)
{
  int i = blockIdx.x * 256 + threadIdx.x;
  if (i >= n8) return;
  const float4* s4 = (const float4*)src;
  float4 a = s4[(size_t)i * 2], b = s4[(size_t)i * 2 + 1];
  f16x8 d;
  d[0] = (f16)a.x; d[1] = (f16)a.y; d[2] = (f16)a.z; d[3] = (f16)a.w;
  d[4] = (f16)b.x; d[5] = (f16)b.y; d[6] = (f16)b.z; d[7] = (f16)b.w;
  *(f16x8*)(dst + (size_t)i * 8) = d;
}

// two equal-size tensors in one dispatch (saves a launch)
__global__ __launch_bounds__(256) void cvt2_kernel(
    const float* __restrict__ s0, const float* __restrict__ s1,
    f16* __restrict__ d0, f16* __restrict__ d1, int n8each)
{
  int i = blockIdx.x * 256 + threadIdx.x;
  const float* src = (i < n8each) ? s0 : s1;
  f16* dst = (i < n8each) ? d0 : d1;
  int k = (i < n8each) ? i : i - n8each;
  if (k >= n8each) return;
  const float4* s4 = (const float4*)src;
  float4 a = s4[(size_t)k * 2], b = s4[(size_t)k * 2 + 1];
  f16x8 d;
  d[0] = (f16)a.x; d[1] = (f16)a.y; d[2] = (f16)a.z; d[3] = (f16)a.w;
  d[4] = (f16)b.x; d[5] = (f16)b.y; d[6] = (f16)b.z; d[7] = (f16)b.w;
  *(f16x8*)(dst + (size_t)k * 8) = d;
}

// ---------------------------------------------------------------------------
// LIF kernel (round-6 geometry + 2-phase split). Tile 128x128, BK=64,
// 8 waves (2Mx4N), wave 64x32 = 4x2 frags; 5 s-slices sequential, per-thread
// (mem,cnt) LIF state, slice boundary every 8th K-tile.
// LDS A,B 2 slots each [128][64] f16 XOR-swizzled = 64KB.
// ---------------------------------------------------------------------------
__global__ __launch_bounds__(512, 1) void lif256_kernel(
    const f16* __restrict__ S,    // [4096*5, 512] fp16 (row (b*5+s))
    const f16* __restrict__ W,    // [2048, 512] fp16
    const float* __restrict__ bl, // [2048] fp32
    f16* __restrict__ X)          // [4096, 2048] fp16
{
  __shared__ alignas(16) f16 lds[4][128 * 64];   // [0,1]=A slots, [2,3]=B slots

  const int tid = threadIdx.x, wid = tid >> 6, lane = tid & 63;
  // XCD swizzle (nwg=512): consecutive wg -> same XCD; bn fastest.
  const int wg = ((int)blockIdx.x % 8) * 64 + (int)blockIdx.x / 8;
  const int bn = wg & 15, bm = wg >> 4;          // nbn=16, nbm=32
  const int b0 = bm * 128, h0 = bn * 128;
  const int wr0 = (wid >> 2) * 64, wc0 = (wid & 3) * 32;
  const int fr = lane & 15, fq = lane >> 4;
  const int sr = tid >> 3, scb = (tid & 7) * 16;  // staging row-in-64, col byte

  f32x4 acc[4][2] = {};
  float mem[4][2][4] = {};
  float cnt[4][2][4] = {};

  auto STAGE = [&](int slot, int g) {
    const int s = g >> 3, k0 = (g & 7) * 64;
#pragma unroll
    for (int l = 0; l < 2; ++l) {
      const int row = l * 64 + sr;
      const int c2 = scb ^ ((row & 7) << 4);      // pre-swizzled source col (bytes)
      gload16(S + ((size_t)(b0 + row) * 5 + s) * 512 + k0 + (c2 >> 1),
              &lds[slot][l * 4096 + tid * 8]);
    }
#pragma unroll
    for (int l = 0; l < 2; ++l) {
      const int row = l * 64 + sr;
      const int c2 = scb ^ ((row & 7) << 4);
      gload16(W + (size_t)(h0 + row) * 512 + k0 + (c2 >> 1),
              &lds[2 + slot][l * 4096 + tid * 8]);
    }
  };

  auto LDA_ = [&](int slot, int mf, int ks) -> f16x8 {
    const int row = wr0 + mf * 16 + fr;
    const int c = (ks * 64 + fq * 16) ^ ((row & 7) << 4);
    return *(const f16x8*)&lds[slot][row * 64 + (c >> 1)];
  };
  auto LDB_ = [&](int slot, int nf, int ks) -> f16x8 {
    const int row = wc0 + nf * 16 + fr;
    const int c = (ks * 64 + fq * 16) ^ ((row & 7) << 4);
    return *(const f16x8*)&lds[2 + slot][row * 64 + (c >> 1)];
  };

  const float bias[2] = { bl[h0 + wc0 + fr], bl[h0 + wc0 + 16 + fr] };

  STAGE(0, 0);
  STAGE(1, 1);
  VMW4();          // tile 0 landed; tile 1's 4 loads stay in flight
  BARRIER();
  SCHED0();

#pragma unroll 2
  for (int g = 0; g < 40; ++g) {
    const int slot = g & 1;

    // ---- P0: B + A-frags {0,1} -> bar -> lgkm0 -> 8 MFMA -> bar
    f16x8 b[2][2], a[2][2];
#pragma unroll
    for (int nf = 0; nf < 2; ++nf) {
      b[nf][0] = LDB_(slot, nf, 0);
      b[nf][1] = LDB_(slot, nf, 1);
    }
#pragma unroll
    for (int i = 0; i < 2; ++i) {
      a[i][0] = LDA_(slot, i, 0);
      a[i][1] = LDA_(slot, i, 1);
    }
    BARRIER(); LGKM0(); SCHED0();
    __builtin_amdgcn_s_setprio(1);
#pragma unroll
    for (int i = 0; i < 2; ++i)
#pragma unroll
      for (int nf = 0; nf < 2; ++nf) {
        acc[i][nf] = MFMA16(a[i][0], b[nf][0], acc[i][nf]);
        acc[i][nf] = MFMA16(a[i][1], b[nf][1], acc[i][nf]);
      }
    __builtin_amdgcn_s_setprio(0);
    BARRIER();

    // ---- P1: A-frags {2,3}; drain-before-bar so slot is dead; stage; MFMA
#pragma unroll
    for (int i = 0; i < 2; ++i) {
      a[i][0] = LDA_(slot, 2 + i, 0);
      a[i][1] = LDA_(slot, 2 + i, 1);
    }
    LGKM0(); SCHED0();
    BARRIER();                 // all waves' reads of this slot complete
    if (g + 2 < 40) STAGE(slot, g + 2);   // overwrite dead slot; stays in flight
    SCHED0();
    __builtin_amdgcn_s_setprio(1);
#pragma unroll
    for (int i = 0; i < 2; ++i)
#pragma unroll
      for (int nf = 0; nf < 2; ++nf) {
        acc[2 + i][nf] = MFMA16(a[i][0], b[nf][0], acc[2 + i][nf]);
        acc[2 + i][nf] = MFMA16(a[i][1], b[nf][1], acc[2 + i][nf]);
      }
    __builtin_amdgcn_s_setprio(0);

    if ((g & 7) == 7) {
      // slice boundary: 3 LIF reps with fc = acc + bias; reset acc
#pragma unroll
      for (int mf = 0; mf < 4; ++mf)
#pragma unroll
        for (int nf = 0; nf < 2; ++nf) {
#pragma unroll
          for (int r = 0; r < 4; ++r) {
            const float fc = acc[mf][nf][r] + bias[nf];
            float m = mem[mf][nf][r], c = cnt[mf][nf][r];
#pragma unroll
            for (int j = 0; j < 3; ++j) {
              m = ((m > 0.2f) ? 0.f : m * 0.2f) + fc;   // DECAY=0.2, spike resets
              c += (m > 0.2f) ? 1.f : 0.f;              // THRESH=0.2
            }
            mem[mf][nf][r] = m; cnt[mf][nf][r] = c;
          }
          acc[mf][nf] = f32x4{0.f, 0.f, 0.f, 0.f};
        }
    }

    if (g + 2 < 40)      { VMW4(); }   // tile g+1 landed (g+2's 4 still flying)
    else if (g + 1 < 40) { VMW0(); }
    BARRIER();
    SCHED0();
  }

#pragma unroll
  for (int nf = 0; nf < 2; ++nf) {
    const int col = h0 + wc0 + nf * 16 + fr;
#pragma unroll
    for (int mf = 0; mf < 4; ++mf) {
      const int row0 = b0 + wr0 + mf * 16 + fq * 4;
#pragma unroll
      for (int r = 0; r < 4; ++r)
        X[(size_t)(row0 + r) * 2048 + col] = (f16)(cnt[mf][nf][r] / 15.0f);
    }
  }
}

// ---------------------------------------------------------------------------
// Trunk GEMM: C = relu(A @ W^T + bias), fp16 in/out, fp32 bias/accum.
// 256x256 tile, BK=64, 8 waves (2Mx4N), wave output 128x64 = 8x4 frags.
// 4 phases per K-tile, each {reads -> bar -> lgkm0 -> 16 MFMA -> bar};
// P3 drains lgkm before its barrier, then stages kt+2 into the dead slot.
// ---------------------------------------------------------------------------
__global__ __launch_bounds__(512, 2) void trunk256_kernel(
    const f16* __restrict__ A0, const f16* __restrict__ A1, int lda,
    const f16* __restrict__ W0, const f16* __restrict__ W1,
    const float* __restrict__ bb0, const float* __restrict__ bb1,
    f16* __restrict__ C0, f16* __restrict__ C1, int ldc,
    int nbm, int nbn_half, int K)
{
  __shared__ alignas(16) f16 lds[4][256 * 64];   // [0,1]=A slots, [2,3]=B slots

  const int tid = threadIdx.x, wid = tid >> 6, lane = tid & 63;
  const int nwg = nbm * nbn_half * 2, q8 = nwg / 8;
  const int wg = ((int)blockIdx.x % 8) * q8 + (int)blockIdx.x / 8;
  const int bmi = wg % nbm, t = wg / nbm;
  const int half = (t >= nbn_half);
  const f16* Ap = half ? A1 : A0;
  const f16* Wp = half ? W1 : W0;
  const float* bias = half ? bb1 : bb0;
  f16* C = half ? C1 : C0;
  const int bm0 = bmi * 256;
  const int bn0 = (half ? t - nbn_half : t) * 256;

  const int wr0 = (wid >> 2) * 128, wc0 = (wid & 3) * 64;
  const int fr = lane & 15, fq = lane >> 4;
  const int sr = tid >> 3, scb = (tid & 7) * 16;

  f32x4 acc[8][4] = {};
  const int NT = K / 64;

  auto STAGE = [&](int slot, int kt) {
    const int k0 = kt * 64;
#pragma unroll
    for (int l = 0; l < 4; ++l) {
      const int row = l * 64 + sr;
      const int c2 = scb ^ ((row & 7) << 4);
      gload16(Ap + (size_t)(bm0 + row) * lda + k0 + (c2 >> 1),
              &lds[slot][l * 4096 + tid * 8]);
    }
#pragma unroll
    for (int l = 0; l < 4; ++l) {
      const int row = l * 64 + sr;
      const int c2 = scb ^ ((row & 7) << 4);
      gload16(Wp + (size_t)(bn0 + row) * K + k0 + (c2 >> 1),
              &lds[2 + slot][l * 4096 + tid * 8]);
    }
  };

  auto LDA_ = [&](int slot, int mf, int ks) -> f16x8 {
    const int row = wr0 + mf * 16 + fr;
    const int c = (ks * 64 + fq * 16) ^ ((row & 7) << 4);
    return *(const f16x8*)&lds[slot][row * 64 + (c >> 1)];
  };
  auto LDB_ = [&](int slot, int nf, int ks) -> f16x8 {
    const int row = wc0 + nf * 16 + fr;
    const int c = (ks * 64 + fq * 16) ^ ((row & 7) << 4);
    return *(const f16x8*)&lds[2 + slot][row * 64 + (c >> 1)];
  };

  STAGE(0, 0);
  STAGE(1, 1);
  VMW8();          // tile 0 landed; tile 1's 8 loads stay in flight
  BARRIER();
  SCHED0();

  for (int kt = 0; kt < NT; ++kt) {
    const int slot = kt & 1;
    f16x8 b[4][2], a[2][2];

    auto QUAD = [&](int mbase) {
      __builtin_amdgcn_s_setprio(1);
#pragma unroll
      for (int nf = 0; nf < 4; ++nf) {
        acc[mbase][nf]     = MFMA16(a[0][0], b[nf][0], acc[mbase][nf]);
        acc[mbase][nf]     = MFMA16(a[0][1], b[nf][1], acc[mbase][nf]);
        acc[mbase + 1][nf] = MFMA16(a[1][0], b[nf][0], acc[mbase + 1][nf]);
        acc[mbase + 1][nf] = MFMA16(a[1][1], b[nf][1], acc[mbase + 1][nf]);
      }
      __builtin_amdgcn_s_setprio(0);
    };

    // ---- P0: B (8 reads) + A-quad0 (4 reads)
#pragma unroll
    for (int nf = 0; nf < 4; ++nf) {
      b[nf][0] = LDB_(slot, nf, 0);
      b[nf][1] = LDB_(slot, nf, 1);
    }
#pragma unroll
    for (int i = 0; i < 2; ++i) { a[i][0] = LDA_(slot, i, 0); a[i][1] = LDA_(slot, i, 1); }
    BARRIER(); LGKM0(); SCHED0();
    QUAD(0);
    BARRIER();

    // ---- P1
#pragma unroll
    for (int i = 0; i < 2; ++i) { a[i][0] = LDA_(slot, 2 + i, 0); a[i][1] = LDA_(slot, 2 + i, 1); }
    BARRIER(); LGKM0(); SCHED0();
    QUAD(2);
    BARRIER();

    // ---- P2
#pragma unroll
    for (int i = 0; i < 2; ++i) { a[i][0] = LDA_(slot, 4 + i, 0); a[i][1] = LDA_(slot, 4 + i, 1); }
    BARRIER(); LGKM0(); SCHED0();
    QUAD(4);
    BARRIER();

    // ---- P3: drain before barrier so slot is dead block-wide, then stage
#pragma unroll
    for (int i = 0; i < 2; ++i) { a[i][0] = LDA_(slot, 6 + i, 0); a[i][1] = LDA_(slot, 6 + i, 1); }
    LGKM0(); SCHED0();
    BARRIER();                  // all waves' reads of this slot complete
    if (kt + 2 < NT) STAGE(slot, kt + 2);
    SCHED0();
    QUAD(6);
    if (kt + 2 < NT)      { VMW8(); }   // tile kt+1 landed (kt+2 still flying)
    else if (kt + 1 < NT) { VMW0(); }
    BARRIER();
    SCHED0();
  }

#pragma unroll
  for (int nf = 0; nf < 4; ++nf) {
    const int col = bn0 + wc0 + nf * 16 + fr;
    const float bv = bias[col];
#pragma unroll
    for (int m = 0; m < 8; ++m) {
      const int row0 = bm0 + wr0 + m * 16 + fq * 4;
#pragma unroll
      for (int r = 0; r < 4; ++r) {
        float v = fmaxf(acc[m][nf][r] + bv, 0.f);
        C[(size_t)(row0 + r) * ldc + col] = (f16)v;
      }
    }
  }
}

// ---------------------------------------------------------------------------
// Heads: mean = h12@Wm^T + bm ; log_std = clip(h22@Wls^T + bls, -20, 2). fp32 out.
// ---------------------------------------------------------------------------
__global__ __launch_bounds__(256) void head_kernel(
    const f16* __restrict__ H1, const f16* __restrict__ H2,
    const f16* __restrict__ Wm, const float* __restrict__ bm,
    const f16* __restrict__ Wls, const float* __restrict__ bls,
    float* __restrict__ OUT, int M, int K)
{
  const int tid = threadIdx.x, wid = tid >> 6, lane = tid & 63;
  const int m0 = blockIdx.x * 64 + wid * 16;
  const int kb = (lane >> 4) * 8, fr = lane & 15, fq = lane >> 4;

  f32x4 a1[2] = {}, a2[2] = {};
  for (int k0 = 0; k0 < K; k0 += 32) {
    f16x8 f1 = *(const f16x8*)&H1[(size_t)(m0 + fr) * K + k0 + kb];
    f16x8 f2 = *(const f16x8*)&H2[(size_t)(m0 + fr) * K + k0 + kb];
#pragma unroll
    for (int n = 0; n < 2; ++n) {
      f16x8 wm = *(const f16x8*)&Wm[(size_t)(n * 16 + fr) * K + k0 + kb];
      f16x8 wl = *(const f16x8*)&Wls[(size_t)(n * 16 + fr) * K + k0 + kb];
      a1[n] = MFMA16(f1, wm, a1[n]);
      a2[n] = MFMA16(f2, wl, a2[n]);
    }
  }

#pragma unroll
  for (int n = 0; n < 2; ++n) {
    const int col = n * 16 + fr;
    const float bvm = bm[col];
    const float bvl = bls[col];
#pragma unroll
    for (int r = 0; r < 4; ++r) {
      const int row = m0 + fq * 4 + r;
      OUT[(size_t)row * 32 + col] = a1[n][r] + bvm;
      float lv = a2[n][r] + bvl;
      OUT[(size_t)M * 32 + (size_t)row * 32 + col] = fminf(fmaxf(lv, -20.f), 2.f);
    }
  }
}

// ---------------------------------------------------------------------------
extern "C" void kernel_launch(void* const* d_in, const int* in_sizes, int n_in,
                              void* d_out, int out_size, void* d_ws, size_t ws_size,
                              hipStream_t stream) {
  const float* state = (const float*)d_in[0];
  const float* W_lif = (const float*)d_in[1];
  const float* b_lif = (const float*)d_in[2];
  const float* W11   = (const float*)d_in[3];
  const float* b11   = (const float*)d_in[4];
  const float* W12   = (const float*)d_in[5];
  const float* b12   = (const float*)d_in[6];
  const float* W21   = (const float*)d_in[7];
  const float* b21   = (const float*)d_in[8];
  const float* W22   = (const float*)d_in[9];
  const float* b22   = (const float*)d_in[10];
  const float* Wm    = (const float*)d_in[11];
  const float* bm    = (const float*)d_in[12];
  const float* Wls   = (const float*)d_in[13];
  const float* bls   = (const float*)d_in[14];
  float* out = (float*)d_out;

  const int B = 4096, IN = 512, H = 2048;
  char* ws = (char*)d_ws;
  // layout (bytes), peak 80.0 MB:
  f16* x    = (f16*)(ws);
  f16* h1   = (f16*)(ws + 16777216);
  f16* h2   = (f16*)(ws + 33554432);
  f16* s16  = (f16*)(ws + 50331648);
  f16* wl16 = (f16*)(ws + 71303168);
  f16* w11h = (f16*)(ws + 50331648);
  f16* w21h = (f16*)(ws + 58720256);
  f16* h22  = (f16*)(ws + 50331648);
  f16* w12h = (f16*)(ws + 67108864);
  f16* w22h = (f16*)(ws + 75497472);
  f16* wmh  = (f16*)(ws + 67108864);
  f16* wlsh = (f16*)(ws + 67239936);
  f16* h12  = x;

  // 1) converts for LIF
  cvt_kernel<<<(B * 5 * IN / 8) / 256, 256, 0, stream>>>(state, s16, B * 5 * IN / 8);
  cvt_kernel<<<(H * IN / 8) / 256, 256, 0, stream>>>(W_lif, wl16, H * IN / 8);

  // 2) fused fc-GEMM + LIF -> x  (2-phase split)
  lif256_kernel<<<512, 512, 0, stream>>>(s16, wl16, b_lif, x);

  // 3) layer-1: cvt W11+W21 (over s16), fused 256^2 GEMM -> h1, h2
  cvt2_kernel<<<2 * (H * H / 8) / 256, 256, 0, stream>>>(W11, W21, w11h, w21h, H * H / 8);
  trunk256_kernel<<<256, 512, 0, stream>>>(x, x, H, w11h, w21h, b11, b21,
                                           h1, h2, H, 16, 8, H);

  // 4) layer-2: cvt W12+W22, fused 256^2 GEMM -> h12 (over x), h22
  cvt2_kernel<<<2 * (H * H / 8) / 256, 256, 0, stream>>>(W12, W22, w12h, w22h, H * H / 8);
  trunk256_kernel<<<256, 512, 0, stream>>>(h1, h2, H, w12h, w22h, b12, b22,
                                           h12, h22, H, 16, 8, H);

  // 5) heads -> d_out = [mean | log_std] fp32
  cvt2_kernel<<<2 * (32 * H / 8) / 256, 256, 0, stream>>>(Wm, Wls, wmh, wlsh, 32 * H / 8);
  head_kernel<<<B / 64, 256, 0, stream>>>(h12, h22, wmh, bm, wlsh, bls, out, B, H);
}

// Round 10
// 277.987 us; speedup vs baseline: 1.1035x; 1.0454x over previous
//
#include <hip/hip_runtime.h>
#include <hip/hip_bf16.h>

// GaussianPolicy: SNN-LIF frontend + 2-branch MLP heads.
// B=4096, IN=512, H=2048, A=32. fp32 in/out; fp16 MFMA compute internally.
// Both GEMM kernels: XOR-swizzled LDS (T2), counted vmcnt (T4), setprio (T5),
// and HOISTED addressing: all ds_read addrs = 4 base regs + compile-time
// immediates (row&7 == fr&7 is frag-invariant). All swizzle arithmetic in BYTES.

typedef _Float16 f16;
using f32x4 = __attribute__((ext_vector_type(4))) float;
using f16x8 = __attribute__((ext_vector_type(8))) f16;   // 8 fp16 = 4 VGPRs

#define MFMA16(a, b, c) __builtin_amdgcn_mfma_f32_16x16x32_f16((a), (b), (c), 0, 0, 0)
#define VMW8()  asm volatile("s_waitcnt vmcnt(8)" ::: "memory")
#define VMW4()  asm volatile("s_waitcnt vmcnt(4)" ::: "memory")
#define VMW0()  asm volatile("s_waitcnt vmcnt(0)" ::: "memory")
#define LGKM0() asm volatile("s_waitcnt lgkmcnt(0)" ::: "memory")
#define BARRIER() __builtin_amdgcn_s_barrier()
#define SCHED0() __builtin_amdgcn_sched_barrier(0)

__device__ __forceinline__ void gload16(const void* g, void* l) {
  // async global->LDS, 16B/lane; LDS dest = wave-uniform base + lane*16
  __builtin_amdgcn_global_load_lds(
      (const __attribute__((address_space(1))) unsigned int*)g,
      (__attribute__((address_space(3))) unsigned int*)l, 16, 0, 0);
}

__device__ __forceinline__ void cvt8(const float4& a, const float4& b, f16* dst) {
  f16x8 d;
  d[0] = (f16)a.x; d[1] = (f16)a.y; d[2] = (f16)a.z; d[3] = (f16)a.w;
  d[4] = (f16)b.x; d[5] = (f16)b.y; d[6] = (f16)b.z; d[7] = (f16)b.w;
  *(f16x8*)dst = d;
}

// ---------------------------------------------------------------------------
// two tensors (unequal sizes) in one dispatch
// ---------------------------------------------------------------------------
__global__ __launch_bounds__(256) void cvt2b_kernel(
    const float* __restrict__ s0, f16* __restrict__ d0, int n8a,
    const float* __restrict__ s1, f16* __restrict__ d1, int n8b)
{
  int i = blockIdx.x * 256 + threadIdx.x;
  const float* src; f16* dst; int k;
  if (i < n8a) { src = s0; dst = d0; k = i; }
  else { k = i - n8a; if (k >= n8b) return; src = s1; dst = d1; }
  const float4* s4 = (const float4*)src;
  float4 a = s4[(size_t)k * 2], b = s4[(size_t)k * 2 + 1];
  cvt8(a, b, dst + (size_t)k * 8);
}

// 4 equal 2^19-n8 tensors -> one contiguous fp16 destination
__global__ __launch_bounds__(256) void cvt4_kernel(
    const float* __restrict__ w0, const float* __restrict__ w1,
    const float* __restrict__ w2, const float* __restrict__ w3,
    f16* __restrict__ dst)
{
  int i = blockIdx.x * 256 + threadIdx.x;     // [0, 4*524288)
  int which = i >> 19, k = i & 524287;
  const float* src = (which == 0) ? w0 : (which == 1) ? w1 : (which == 2) ? w2 : w3;
  const float4* s4 = (const float4*)src;
  float4 a = s4[(size_t)k * 2], b = s4[(size_t)k * 2 + 1];
  cvt8(a, b, dst + (size_t)i * 8);
}

// two equal-size tensors in one dispatch (heads)
__global__ __launch_bounds__(256) void cvt2_kernel(
    const float* __restrict__ s0, const float* __restrict__ s1,
    f16* __restrict__ d0, f16* __restrict__ d1, int n8each)
{
  int i = blockIdx.x * 256 + threadIdx.x;
  const float* src = (i < n8each) ? s0 : s1;
  f16* dst = (i < n8each) ? d0 : d1;
  int k = (i < n8each) ? i : i - n8each;
  if (k >= n8each) return;
  const float4* s4 = (const float4*)src;
  float4 a = s4[(size_t)k * 2], b = s4[(size_t)k * 2 + 1];
  cvt8(a, b, dst + (size_t)k * 8);
}

// ---------------------------------------------------------------------------
// LIF kernel. Tile 128(M=batch) x 128(N=hidden), BK=64, 8 waves (2Mx4N),
// wave 64x32 = 4x2 frags; 5 s-slices sequential (g in [0,40), s=g>>3);
// per-thread (mem,cnt) LIF state, slice boundary every 8th K-tile.
// LDS A,B 2 slots each [128][64] f16 XOR-swizzled = 64KB. Hoisted addressing.
// ---------------------------------------------------------------------------
__global__ __launch_bounds__(512, 1) void lif256_kernel(
    const f16* __restrict__ S,    // [4096*5, 512] fp16 (row (b*5+s))
    const f16* __restrict__ W,    // [2048, 512] fp16
    const float* __restrict__ bl, // [2048] fp32
    f16* __restrict__ X)          // [4096, 2048] fp16
{
  __shared__ alignas(16) f16 lds[4][128 * 64];   // [0,1]=A slots, [2,3]=B slots

  const int tid = threadIdx.x, wid = tid >> 6, lane = tid & 63;
  const int wg = ((int)blockIdx.x % 8) * 64 + (int)blockIdx.x / 8;
  const int bn = wg & 15, bm = wg >> 4;          // nbn=16, nbm=32
  const int b0 = bm * 128, h0 = bn * 128;
  const int wr0 = (wid >> 2) * 64, wc0 = (wid & 3) * 32;
  const int fr = lane & 15, fq = lane >> 4;
  const int sr = tid >> 3, scb = (tid & 7) * 16;  // staging row-in-64, col byte

  f32x4 acc[4][2] = {};
  float mem[4][2][4] = {};
  float cnt[4][2][4] = {};

  // ---- hoisted LDS read bases (ALL BYTE ARITHMETIC, row stride 128 B);
  //      read = base + slot*16384 + frag*2048
  char* Lb = (char*)&lds[0][0];
  const int xsw = (fr & 7) << 4;                  // byte-space XOR operand
  const int x0 = (fq * 16) ^ xsw;                 // ks=0 col bytes
  const int x1 = (64 + fq * 16) ^ xsw;            // ks=1 col bytes
  char* const pA0 = Lb + (wr0 + fr) * 128 + x0;
  char* const pA1 = Lb + (wr0 + fr) * 128 + x1;
  char* const pB0 = Lb + 32768 + (wc0 + fr) * 128 + x0;
  char* const pB1 = Lb + 32768 + (wc0 + fr) * 128 + x1;

  // ---- hoisted staging bases (per-l fixed pointer + scalar k-offset)
  const f16* sBase[2]; const f16* wBase[2];
#pragma unroll
  for (int l = 0; l < 2; ++l) {
    const int row = l * 64 + sr;
    const int c2 = scb ^ ((row & 7) << 4);        // bytes (pre-swizzled src)
    sBase[l] = S + (size_t)(b0 + row) * 2560 + (c2 >> 1);
    wBase[l] = W + (size_t)(h0 + row) * 512 + (c2 >> 1);
  }

  auto STAGE = [&](int slot, int g) {
    const int koff = (g >> 3) * 512 + (g & 7) * 64;   // elements into S row
    const int kw = (g & 7) * 64;
#pragma unroll
    for (int l = 0; l < 2; ++l)
      gload16(sBase[l] + koff, Lb + slot * 16384 + l * 8192 + tid * 16);
#pragma unroll
    for (int l = 0; l < 2; ++l)
      gload16(wBase[l] + kw, Lb + 32768 + slot * 16384 + l * 8192 + tid * 16);
  };

  const float bias[2] = { bl[h0 + wc0 + fr], bl[h0 + wc0 + 16 + fr] };

  STAGE(0, 0);
  STAGE(1, 1);
  VMW4();          // tile 0 landed; tile 1's 4 loads stay in flight
  BARRIER();
  SCHED0();

#pragma unroll 2
  for (int g = 0; g < 40; ++g) {
    const int slot = g & 1;                  // compile-time under unroll-2
    const int so = slot * 16384;

    // ---- P0: B + A-frags {0,1} -> bar -> lgkm0 -> 8 MFMA -> bar
    f16x8 b[2][2], a[2][2];
#pragma unroll
    for (int nf = 0; nf < 2; ++nf) {
      b[nf][0] = *(const f16x8*)(pB0 + so + nf * 2048);
      b[nf][1] = *(const f16x8*)(pB1 + so + nf * 2048);
    }
#pragma unroll
    for (int i = 0; i < 2; ++i) {
      a[i][0] = *(const f16x8*)(pA0 + so + i * 2048);
      a[i][1] = *(const f16x8*)(pA1 + so + i * 2048);
    }
    BARRIER(); LGKM0(); SCHED0();
    __builtin_amdgcn_s_setprio(1);
#pragma unroll
    for (int i = 0; i < 2; ++i)
#pragma unroll
      for (int nf = 0; nf < 2; ++nf) {
        acc[i][nf] = MFMA16(a[i][0], b[nf][0], acc[i][nf]);
        acc[i][nf] = MFMA16(a[i][1], b[nf][1], acc[i][nf]);
      }
    __builtin_amdgcn_s_setprio(0);
    BARRIER();

    // ---- P1: A-frags {2,3}; drain-before-bar so slot is dead; stage; MFMA
#pragma unroll
    for (int i = 0; i < 2; ++i) {
      a[i][0] = *(const f16x8*)(pA0 + so + (2 + i) * 2048);
      a[i][1] = *(const f16x8*)(pA1 + so + (2 + i) * 2048);
    }
    LGKM0(); SCHED0();
    BARRIER();                 // all waves' reads of this slot complete
    if (g + 2 < 40) STAGE(slot, g + 2);   // overwrite dead slot; stays in flight
    SCHED0();
    __builtin_amdgcn_s_setprio(1);
#pragma unroll
    for (int i = 0; i < 2; ++i)
#pragma unroll
      for (int nf = 0; nf < 2; ++nf) {
        acc[2 + i][nf] = MFMA16(a[i][0], b[nf][0], acc[2 + i][nf]);
        acc[2 + i][nf] = MFMA16(a[i][1], b[nf][1], acc[2 + i][nf]);
      }
    __builtin_amdgcn_s_setprio(0);

    if ((g & 7) == 7) {
      // slice boundary: 3 LIF reps with fc = acc + bias; reset acc
#pragma unroll
      for (int mf = 0; mf < 4; ++mf)
#pragma unroll
        for (int nf = 0; nf < 2; ++nf) {
#pragma unroll
          for (int r = 0; r < 4; ++r) {
            const float fc = acc[mf][nf][r] + bias[nf];
            float m = mem[mf][nf][r], c = cnt[mf][nf][r];
#pragma unroll
            for (int j = 0; j < 3; ++j) {
              m = ((m > 0.2f) ? 0.f : m * 0.2f) + fc;   // DECAY=0.2, spike resets
              c += (m > 0.2f) ? 1.f : 0.f;              // THRESH=0.2
            }
            mem[mf][nf][r] = m; cnt[mf][nf][r] = c;
          }
          acc[mf][nf] = f32x4{0.f, 0.f, 0.f, 0.f};
        }
    }

    if (g + 2 < 40)      { VMW4(); }   // tile g+1 landed (g+2's 4 still flying)
    else if (g + 1 < 40) { VMW0(); }
    BARRIER();
    SCHED0();
  }

#pragma unroll
  for (int nf = 0; nf < 2; ++nf) {
    const int col = h0 + wc0 + nf * 16 + fr;
#pragma unroll
    for (int mf = 0; mf < 4; ++mf) {
      const int row0 = b0 + wr0 + mf * 16 + fq * 4;
#pragma unroll
      for (int r = 0; r < 4; ++r)
        X[(size_t)(row0 + r) * 2048 + col] = (f16)(cnt[mf][nf][r] / 15.0f);
    }
  }
}

// ---------------------------------------------------------------------------
// Trunk GEMM: C = relu(A @ W^T + bias), fp16 in/out, fp32 bias/accum.
// 256x256 tile, BK=64, 8 waves (2Mx4N), wave 128x64 = 8x4 frags.
// Round-5 QUAD schedule + hoisted addressing. Dual column-halves (fusion).
// ---------------------------------------------------------------------------
__global__ __launch_bounds__(512, 2) void trunk256_kernel(
    const f16* __restrict__ A0, const f16* __restrict__ A1, int lda,
    const f16* __restrict__ W0, const f16* __restrict__ W1,
    const float* __restrict__ bb0, const float* __restrict__ bb1,
    f16* __restrict__ C0, f16* __restrict__ C1, int ldc,
    int nbm, int nbn_half, int K)
{
  __shared__ alignas(16) f16 lds[4][256 * 64];   // [0,1]=A slots, [2,3]=B slots

  const int tid = threadIdx.x, wid = tid >> 6, lane = tid & 63;
  const int nwg = nbm * nbn_half * 2, q8 = nwg / 8;
  const int wg = ((int)blockIdx.x % 8) * q8 + (int)blockIdx.x / 8;
  const int bmi = wg % nbm, t = wg / nbm;
  const int half = (t >= nbn_half);
  const f16* Ap = half ? A1 : A0;
  const f16* Wp = half ? W1 : W0;
  const float* bias = half ? bb1 : bb0;
  f16* C = half ? C1 : C0;
  const int bm0 = bmi * 256;
  const int bn0 = (half ? t - nbn_half : t) * 256;

  const int wr0 = (wid >> 2) * 128, wc0 = (wid & 3) * 64;
  const int fr = lane & 15, fq = lane >> 4;
  const int sr = tid >> 3, scb = (tid & 7) * 16;

  f32x4 acc[8][4] = {};
  const int NT = K / 64;

  // ---- hoisted LDS read bases (BYTES, row stride 128 B);
  //      read = base + slot*32768 + frag*2048
  char* Lb = (char*)&lds[0][0];
  const int xsw = (fr & 7) << 4;
  const int x0 = (fq * 16) ^ xsw;
  const int x1 = (64 + fq * 16) ^ xsw;
  char* const pA0 = Lb + (wr0 + fr) * 128 + x0;
  char* const pA1 = Lb + (wr0 + fr) * 128 + x1;
  char* const pB0 = Lb + 65536 + (wc0 + fr) * 128 + x0;
  char* const pB1 = Lb + 65536 + (wc0 + fr) * 128 + x1;

  // ---- hoisted staging bases
  const f16* aBase[4]; const f16* wBase[4];
#pragma unroll
  for (int l = 0; l < 4; ++l) {
    const int row = l * 64 + sr;
    const int c2 = scb ^ ((row & 7) << 4);
    aBase[l] = Ap + (size_t)(bm0 + row) * lda + (c2 >> 1);
    wBase[l] = Wp + (size_t)(bn0 + row) * K + (c2 >> 1);
  }

  auto STAGE = [&](int slot, int kt) {
    const int koff = kt * 64;
#pragma unroll
    for (int l = 0; l < 4; ++l)
      gload16(aBase[l] + koff, Lb + slot * 32768 + l * 8192 + tid * 16);
#pragma unroll
    for (int l = 0; l < 4; ++l)
      gload16(wBase[l] + koff, Lb + 65536 + slot * 32768 + l * 8192 + tid * 16);
  };

  STAGE(0, 0);
  STAGE(1, 1);
  VMW8();          // tile 0 landed; tile 1's 8 loads stay in flight
  BARRIER();
  SCHED0();

#pragma unroll 2
  for (int kt = 0; kt < NT; ++kt) {
    const int slot = kt & 1;                 // compile-time under unroll-2
    const int so = slot * 32768;

    f16x8 b[4][2];
#pragma unroll
    for (int nf = 0; nf < 4; ++nf) {
      b[nf][0] = *(const f16x8*)(pB0 + so + nf * 2048);
      b[nf][1] = *(const f16x8*)(pB1 + so + nf * 2048);
    }
    f16x8 a0[2][2], a1[2][2];
#pragma unroll
    for (int i = 0; i < 2; ++i) {
      a0[i][0] = *(const f16x8*)(pA0 + so + i * 2048);
      a0[i][1] = *(const f16x8*)(pA1 + so + i * 2048);
    }

    auto QUAD = [&](int mbase, f16x8 (&a)[2][2]) {
      __builtin_amdgcn_s_setprio(1);
#pragma unroll
      for (int nf = 0; nf < 4; ++nf) {
        acc[mbase][nf]     = MFMA16(a[0][0], b[nf][0], acc[mbase][nf]);
        acc[mbase][nf]     = MFMA16(a[0][1], b[nf][1], acc[mbase][nf]);
        acc[mbase + 1][nf] = MFMA16(a[1][0], b[nf][0], acc[mbase + 1][nf]);
        acc[mbase + 1][nf] = MFMA16(a[1][1], b[nf][1], acc[mbase + 1][nf]);
      }
      __builtin_amdgcn_s_setprio(0);
    };

    // quadrant pipeline: read next A-pair while MFMAing current (reg-only)
#pragma unroll
    for (int i = 0; i < 2; ++i) {
      a1[i][0] = *(const f16x8*)(pA0 + so + (2 + i) * 2048);
      a1[i][1] = *(const f16x8*)(pA1 + so + (2 + i) * 2048);
    }
    QUAD(0, a0);
#pragma unroll
    for (int i = 0; i < 2; ++i) {
      a0[i][0] = *(const f16x8*)(pA0 + so + (4 + i) * 2048);
      a0[i][1] = *(const f16x8*)(pA1 + so + (4 + i) * 2048);
    }
    QUAD(2, a1);
#pragma unroll
    for (int i = 0; i < 2; ++i) {
      a1[i][0] = *(const f16x8*)(pA0 + so + (6 + i) * 2048);
      a1[i][1] = *(const f16x8*)(pA1 + so + (6 + i) * 2048);
    }
    QUAD(4, a0);
    QUAD(6, a1);

    LGKM0();        // all reads of this slot complete
    BARRIER();      // ... in every wave
    SCHED0();
    if (kt + 2 < NT) {
      STAGE(slot, kt + 2);   // overwrite now-dead slot; stays in flight
      SCHED0();
      VMW8();                // tile kt+1 landed (kt+2's 8 still flying)
    } else if (kt + 1 < NT) {
      VMW0();
    }
    BARRIER();
    SCHED0();
  }

#pragma unroll
  for (int nf = 0; nf < 4; ++nf) {
    const int col = bn0 + wc0 + nf * 16 + fr;
    const float bv = bias[col];
#pragma unroll
    for (int m = 0; m < 8; ++m) {
      const int row0 = bm0 + wr0 + m * 16 + fq * 4;
#pragma unroll
      for (int r = 0; r < 4; ++r) {
        float v = fmaxf(acc[m][nf][r] + bv, 0.f);
        C[(size_t)(row0 + r) * ldc + col] = (f16)v;
      }
    }
  }
}

// ---------------------------------------------------------------------------
// Heads: mean = h12@Wm^T + bm ; log_std = clip(h22@Wls^T + bls, -20, 2). fp32 out.
// ---------------------------------------------------------------------------
__global__ __launch_bounds__(256) void head_kernel(
    const f16* __restrict__ H1, const f16* __restrict__ H2,
    const f16* __restrict__ Wm, const float* __restrict__ bm,
    const f16* __restrict__ Wls, const float* __restrict__ bls,
    float* __restrict__ OUT, int M, int K)
{
  const int tid = threadIdx.x, wid = tid >> 6, lane = tid & 63;
  const int m0 = blockIdx.x * 64 + wid * 16;
  const int kb = (lane >> 4) * 8, fr = lane & 15, fq = lane >> 4;

  f32x4 a1[2] = {}, a2[2] = {};
  for (int k0 = 0; k0 < K; k0 += 32) {
    f16x8 f1 = *(const f16x8*)&H1[(size_t)(m0 + fr) * K + k0 + kb];
    f16x8 f2 = *(const f16x8*)&H2[(size_t)(m0 + fr) * K + k0 + kb];
#pragma unroll
    for (int n = 0; n < 2; ++n) {
      f16x8 wm = *(const f16x8*)&Wm[(size_t)(n * 16 + fr) * K + k0 + kb];
      f16x8 wl = *(const f16x8*)&Wls[(size_t)(n * 16 + fr) * K + k0 + kb];
      a1[n] = MFMA16(f1, wm, a1[n]);
      a2[n] = MFMA16(f2, wl, a2[n]);
    }
  }

#pragma unroll
  for (int n = 0; n < 2; ++n) {
    const int col = n * 16 + fr;
    const float bvm = bm[col];
    const float bvl = bls[col];
#pragma unroll
    for (int r = 0; r < 4; ++r) {
      const int row = m0 + fq * 4 + r;
      OUT[(size_t)row * 32 + col] = a1[n][r] + bvm;
      float lv = a2[n][r] + bvl;
      OUT[(size_t)M * 32 + (size_t)row * 32 + col] = fminf(fmaxf(lv, -20.f), 2.f);
    }
  }
}

// ---------------------------------------------------------------------------
extern "C" void kernel_launch(void* const* d_in, const int* in_sizes, int n_in,
                              void* d_out, int out_size, void* d_ws, size_t ws_size,
                              hipStream_t stream) {
  const float* state = (const float*)d_in[0];
  const float* W_lif = (const float*)d_in[1];
  const float* b_lif = (const float*)d_in[2];
  const float* W11   = (const float*)d_in[3];
  const float* b11   = (const float*)d_in[4];
  const float* W12   = (const float*)d_in[5];
  const float* b12   = (const float*)d_in[6];
  const float* W21   = (const float*)d_in[7];
  const float* b21   = (const float*)d_in[8];
  const float* W22   = (const float*)d_in[9];
  const float* b22   = (const float*)d_in[10];
  const float* Wm    = (const float*)d_in[11];
  const float* bm    = (const float*)d_in[12];
  const float* Wls   = (const float*)d_in[13];
  const float* bls   = (const float*)d_in[14];
  float* out = (float*)d_out;

  const int B = 4096, IN = 512, H = 2048;
  char* ws = (char*)d_ws;
  // layout (bytes), peak 80.0 MB:
  //   0        x [16.8M] -> h12 (trunk2 out)
  //   16777216 h1 [16.8M]
  //   33554432 h2 [16.8M]
  //   50331648 s16 [21M, lif] -> w11h/w21h/w12h/w22h [33.6M contiguous] -> h22
  //   71303168 wl16 [2M]  (inside the W region; dead before cvt4 runs)
  f16* x    = (f16*)(ws);
  f16* h1   = (f16*)(ws + 16777216);
  f16* h2   = (f16*)(ws + 33554432);
  f16* s16  = (f16*)(ws + 50331648);
  f16* wl16 = (f16*)(ws + 71303168);
  f16* w4   = (f16*)(ws + 50331648);           // w11h|w21h|w12h|w22h contiguous
  f16* w11h = (f16*)(ws + 50331648);
  f16* w21h = (f16*)(ws + 58720256);
  f16* w12h = (f16*)(ws + 67108864);
  f16* w22h = (f16*)(ws + 75497472);
  f16* h22  = (f16*)(ws + 50331648);
  f16* wmh  = (f16*)(ws + 67108864);           // over w12h (dead after trunk2)
  f16* wlsh = (f16*)(ws + 67239936);
  f16* h12  = x;

  // 1) converts for LIF (state + W_lif in one dispatch)
  const int n8s = B * 5 * IN / 8, n8w = H * IN / 8;
  cvt2b_kernel<<<(n8s + n8w + 255) / 256, 256, 0, stream>>>(
      state, s16, n8s, W_lif, wl16, n8w);

  // 2) fused fc-GEMM + LIF -> x
  lif256_kernel<<<512, 512, 0, stream>>>(s16, wl16, b_lif, x);

  // 3) all four trunk weights -> contiguous fp16 (over s16, dead now)
  cvt4_kernel<<<4 * 524288 / 256, 256, 0, stream>>>(W11, W21, W12, W22, w4);

  // 4) trunk layer-1 (fused dual-output), then layer-2
  trunk256_kernel<<<256, 512, 0, stream>>>(x, x, H, w11h, w21h, b11, b21,
                                           h1, h2, H, 16, 8, H);
  trunk256_kernel<<<256, 512, 0, stream>>>(h1, h2, H, w12h, w22h, b12, b22,
                                           h12, h22, H, 16, 8, H);

  // 5) heads -> d_out = [mean | log_std] fp32
  cvt2_kernel<<<2 * (32 * H / 8) / 256, 256, 0, stream>>>(Wm, Wls, wmh, wlsh, 32 * H / 8);
  head_kernel<<<B / 64, 256, 0, stream>>>(h12, h22, wmh, bm, wlsh, bls, out, B, H);
}

// Round 11
// 269.234 us; speedup vs baseline: 1.1394x; 1.0325x over previous
//
#include <hip/hip_runtime.h>
#include <hip/hip_bf16.h>

// GaussianPolicy: SNN-LIF frontend + 2-branch MLP heads.
// B=4096, IN=512, H=2048, A=32. fp32 in/out; fp16 MFMA compute internally.
// Trunk: 256x256/BK64, XOR-swizzled LDS, QUAD schedule, counted vmcnt (proven).
// LIF: 128x128/BK64 with 3-slot LDS ring, stage-at-top, ONE barrier per iter.

typedef _Float16 f16;
using f32x4 = __attribute__((ext_vector_type(4))) float;
using f16x8 = __attribute__((ext_vector_type(8))) f16;   // 8 fp16 = 4 VGPRs

#define MFMA16(a, b, c) __builtin_amdgcn_mfma_f32_16x16x32_f16((a), (b), (c), 0, 0, 0)
#define VMW8()  asm volatile("s_waitcnt vmcnt(8)" ::: "memory")
#define VMW4()  asm volatile("s_waitcnt vmcnt(4)" ::: "memory")
#define VMW0()  asm volatile("s_waitcnt vmcnt(0)" ::: "memory")
#define LGKM0() asm volatile("s_waitcnt lgkmcnt(0)" ::: "memory")
#define BARRIER() __builtin_amdgcn_s_barrier()
#define SCHED0() __builtin_amdgcn_sched_barrier(0)

__device__ __forceinline__ void gload16(const void* g, void* l) {
  // async global->LDS, 16B/lane; LDS dest = wave-uniform base + lane*16
  __builtin_amdgcn_global_load_lds(
      (const __attribute__((address_space(1))) unsigned int*)g,
      (__attribute__((address_space(3))) unsigned int*)l, 16, 0, 0);
}

__device__ __forceinline__ void cvt8(const float4& a, const float4& b, f16* dst) {
  f16x8 d;
  d[0] = (f16)a.x; d[1] = (f16)a.y; d[2] = (f16)a.z; d[3] = (f16)a.w;
  d[4] = (f16)b.x; d[5] = (f16)b.y; d[6] = (f16)b.z; d[7] = (f16)b.w;
  *(f16x8*)dst = d;
}

// ---------------------------------------------------------------------------
// two tensors (unequal sizes) in one dispatch
// ---------------------------------------------------------------------------
__global__ __launch_bounds__(256) void cvt2b_kernel(
    const float* __restrict__ s0, f16* __restrict__ d0, int n8a,
    const float* __restrict__ s1, f16* __restrict__ d1, int n8b)
{
  int i = blockIdx.x * 256 + threadIdx.x;
  const float* src; f16* dst; int k;
  if (i < n8a) { src = s0; dst = d0; k = i; }
  else { k = i - n8a; if (k >= n8b) return; src = s1; dst = d1; }
  const float4* s4 = (const float4*)src;
  float4 a = s4[(size_t)k * 2], b = s4[(size_t)k * 2 + 1];
  cvt8(a, b, dst + (size_t)k * 8);
}

// 4 equal 2^19-n8 tensors -> one contiguous fp16 destination
__global__ __launch_bounds__(256) void cvt4_kernel(
    const float* __restrict__ w0, const float* __restrict__ w1,
    const float* __restrict__ w2, const float* __restrict__ w3,
    f16* __restrict__ dst)
{
  int i = blockIdx.x * 256 + threadIdx.x;     // [0, 4*524288)
  int which = i >> 19, k = i & 524287;
  const float* src = (which == 0) ? w0 : (which == 1) ? w1 : (which == 2) ? w2 : w3;
  const float4* s4 = (const float4*)src;
  float4 a = s4[(size_t)k * 2], b = s4[(size_t)k * 2 + 1];
  cvt8(a, b, dst + (size_t)i * 8);
}

// two equal-size tensors in one dispatch (heads)
__global__ __launch_bounds__(256) void cvt2_kernel(
    const float* __restrict__ s0, const float* __restrict__ s1,
    f16* __restrict__ d0, f16* __restrict__ d1, int n8each)
{
  int i = blockIdx.x * 256 + threadIdx.x;
  const float* src = (i < n8each) ? s0 : s1;
  f16* dst = (i < n8each) ? d0 : d1;
  int k = (i < n8each) ? i : i - n8each;
  if (k >= n8each) return;
  const float4* s4 = (const float4*)src;
  float4 a = s4[(size_t)k * 2], b = s4[(size_t)k * 2 + 1];
  cvt8(a, b, dst + (size_t)k * 8);
}

// ---------------------------------------------------------------------------
// LIF kernel. Tile 128(M=batch) x 128(N=hidden), BK=64, 8 waves (2Mx4N),
// wave 64x32 = 4x2 frags; 5 s-slices sequential (g in [0,40), s=g>>3);
// per-thread (mem,cnt) LIF state, slice boundary every 8th K-tile.
// LDS: 3-slot ring per operand, 96KB. Per iter: STAGE(g+2) at top (slot was
// drained at end of iter g-1), 12 ds_reads, 16 MFMA, LGKM0+VMW4+BARRIER.
// Invariant: every vm/lgkm wait precedes the single barrier (publishes
// completion cross-wave before any dependent read/overwrite).
// ---------------------------------------------------------------------------
__global__ __launch_bounds__(512, 1) void lif256_kernel(
    const f16* __restrict__ S,    // [4096*5, 512] fp16 (row (b*5+s))
    const f16* __restrict__ W,    // [2048, 512] fp16
    const float* __restrict__ bl, // [2048] fp32
    f16* __restrict__ X)          // [4096, 2048] fp16
{
  __shared__ alignas(16) f16 lds[6][128 * 64];   // [0..2]=A ring, [3..5]=B ring

  const int tid = threadIdx.x, wid = tid >> 6, lane = tid & 63;
  const int wg = ((int)blockIdx.x % 8) * 64 + (int)blockIdx.x / 8;
  const int bn = wg & 15, bm = wg >> 4;          // nbn=16, nbm=32
  const int b0 = bm * 128, h0 = bn * 128;
  const int wr0 = (wid >> 2) * 64, wc0 = (wid & 3) * 32;
  const int fr = lane & 15, fq = lane >> 4;
  const int sr = tid >> 3, scb = (tid & 7) * 16;  // staging row-in-64, col byte

  f32x4 acc[4][2] = {};
  float mem[4][2][4] = {};
  float cnt[4][2][4] = {};

  // ---- hoisted LDS read bases (BYTES, row stride 128 B);
  //      read = base + soRead + frag*2048  (soRead in {0,16384,32768})
  char* Lb = (char*)&lds[0][0];
  const int xsw = (fr & 7) << 4;                  // byte-space XOR operand
  const int x0 = (fq * 16) ^ xsw;                 // ks=0 col bytes
  const int x1 = (64 + fq * 16) ^ xsw;            // ks=1 col bytes
  char* const pA0 = Lb + (wr0 + fr) * 128 + x0;
  char* const pA1 = Lb + (wr0 + fr) * 128 + x1;
  char* const pB0 = Lb + 49152 + (wc0 + fr) * 128 + x0;
  char* const pB1 = Lb + 49152 + (wc0 + fr) * 128 + x1;

  // ---- hoisted staging bases (per-l fixed pointer + scalar k-offset)
  const f16* sBase[2]; const f16* wBase[2];
#pragma unroll
  for (int l = 0; l < 2; ++l) {
    const int row = l * 64 + sr;
    const int c2 = scb ^ ((row & 7) << 4);        // bytes (pre-swizzled src)
    sBase[l] = S + (size_t)(b0 + row) * 2560 + (c2 >> 1);
    wBase[l] = W + (size_t)(h0 + row) * 512 + (c2 >> 1);
  }

  auto STAGE = [&](int soSt, int g) {
    const int koff = (g >> 3) * 512 + (g & 7) * 64;   // elements into S row
    const int kw = (g & 7) * 64;
#pragma unroll
    for (int l = 0; l < 2; ++l)
      gload16(sBase[l] + koff, Lb + soSt + l * 8192 + tid * 16);
#pragma unroll
    for (int l = 0; l < 2; ++l)
      gload16(wBase[l] + kw, Lb + 49152 + soSt + l * 8192 + tid * 16);
  };

  const float bias[2] = { bl[h0 + wc0 + fr], bl[h0 + wc0 + 16 + fr] };

  // prologue: tiles 0,1 into slots 0,1; tile 0 must be landed block-wide
  STAGE(0, 0);
  STAGE(16384, 1);
  VMW4();          // tile 0 landed (tile 1's 4 loads in flight)
  BARRIER();
  SCHED0();

  int soRead = 0, soStage = 32768;
  for (int g = 0; g < 40; ++g) {
    // stage tile g+2 into the slot drained at end of iter g-1
    if (g + 2 < 40) STAGE(soStage, g + 2);
    SCHED0();

    // 12 ds_reads of slot g%3 (landed: VMW+barrier of iter g-1)
    f16x8 b[2][2], a0[2][2], a1[2][2];
#pragma unroll
    for (int nf = 0; nf < 2; ++nf) {
      b[nf][0] = *(const f16x8*)(pB0 + soRead + nf * 2048);
      b[nf][1] = *(const f16x8*)(pB1 + soRead + nf * 2048);
    }
#pragma unroll
    for (int i = 0; i < 2; ++i) {
      a0[i][0] = *(const f16x8*)(pA0 + soRead + i * 2048);
      a0[i][1] = *(const f16x8*)(pA1 + soRead + i * 2048);
      a1[i][0] = *(const f16x8*)(pA0 + soRead + (2 + i) * 2048);
      a1[i][1] = *(const f16x8*)(pA1 + soRead + (2 + i) * 2048);
    }

    __builtin_amdgcn_s_setprio(1);
#pragma unroll
    for (int i = 0; i < 2; ++i)
#pragma unroll
      for (int nf = 0; nf < 2; ++nf) {
        acc[i][nf] = MFMA16(a0[i][0], b[nf][0], acc[i][nf]);
        acc[i][nf] = MFMA16(a0[i][1], b[nf][1], acc[i][nf]);
      }
#pragma unroll
    for (int i = 0; i < 2; ++i)
#pragma unroll
      for (int nf = 0; nf < 2; ++nf) {
        acc[2 + i][nf] = MFMA16(a1[i][0], b[nf][0], acc[2 + i][nf]);
        acc[2 + i][nf] = MFMA16(a1[i][1], b[nf][1], acc[2 + i][nf]);
      }
    __builtin_amdgcn_s_setprio(0);

    if ((g & 7) == 7) {
      // slice boundary: 3 LIF reps with fc = acc + bias; reset acc
#pragma unroll
      for (int mf = 0; mf < 4; ++mf)
#pragma unroll
        for (int nf = 0; nf < 2; ++nf) {
#pragma unroll
          for (int r = 0; r < 4; ++r) {
            const float fc = acc[mf][nf][r] + bias[nf];
            float m = mem[mf][nf][r], c = cnt[mf][nf][r];
#pragma unroll
            for (int j = 0; j < 3; ++j) {
              m = ((m > 0.2f) ? 0.f : m * 0.2f) + fc;   // DECAY=0.2, spike resets
              c += (m > 0.2f) ? 1.f : 0.f;              // THRESH=0.2
            }
            mem[mf][nf][r] = m; cnt[mf][nf][r] = c;
          }
          acc[mf][nf] = f32x4{0.f, 0.f, 0.f, 0.f};
        }
    }

    // publish: my reads of slot g%3 done; tile g+1 landed (g+2 stays in flight)
    LGKM0();
    if (g + 2 < 40)      { VMW4(); }
    else if (g + 1 < 40) { VMW0(); }
    BARRIER();
    SCHED0();

    soRead  = (soRead  == 32768) ? 0 : soRead  + 16384;
    soStage = (soStage == 32768) ? 0 : soStage + 16384;
  }

#pragma unroll
  for (int nf = 0; nf < 2; ++nf) {
    const int col = h0 + wc0 + nf * 16 + fr;
#pragma unroll
    for (int mf = 0; mf < 4; ++mf) {
      const int row0 = b0 + wr0 + mf * 16 + fq * 4;
#pragma unroll
      for (int r = 0; r < 4; ++r)
        X[(size_t)(row0 + r) * 2048 + col] = (f16)(cnt[mf][nf][r] / 15.0f);
    }
  }
}

// ---------------------------------------------------------------------------
// Trunk GEMM: C = relu(A @ W^T + bias), fp16 in/out, fp32 bias/accum.
// 256x256 tile, BK=64, 8 waves (2Mx4N), wave 128x64 = 8x4 frags.
// QUAD schedule + hoisted addressing. Dual column-halves (fusion). (proven)
// ---------------------------------------------------------------------------
__global__ __launch_bounds__(512, 2) void trunk256_kernel(
    const f16* __restrict__ A0, const f16* __restrict__ A1, int lda,
    const f16* __restrict__ W0, const f16* __restrict__ W1,
    const float* __restrict__ bb0, const float* __restrict__ bb1,
    f16* __restrict__ C0, f16* __restrict__ C1, int ldc,
    int nbm, int nbn_half, int K)
{
  __shared__ alignas(16) f16 lds[4][256 * 64];   // [0,1]=A slots, [2,3]=B slots

  const int tid = threadIdx.x, wid = tid >> 6, lane = tid & 63;
  const int nwg = nbm * nbn_half * 2, q8 = nwg / 8;
  const int wg = ((int)blockIdx.x % 8) * q8 + (int)blockIdx.x / 8;
  const int bmi = wg % nbm, t = wg / nbm;
  const int half = (t >= nbn_half);
  const f16* Ap = half ? A1 : A0;
  const f16* Wp = half ? W1 : W0;
  const float* bias = half ? bb1 : bb0;
  f16* C = half ? C1 : C0;
  const int bm0 = bmi * 256;
  const int bn0 = (half ? t - nbn_half : t) * 256;

  const int wr0 = (wid >> 2) * 128, wc0 = (wid & 3) * 64;
  const int fr = lane & 15, fq = lane >> 4;
  const int sr = tid >> 3, scb = (tid & 7) * 16;

  f32x4 acc[8][4] = {};
  const int NT = K / 64;

  // ---- hoisted LDS read bases (BYTES, row stride 128 B)
  char* Lb = (char*)&lds[0][0];
  const int xsw = (fr & 7) << 4;
  const int x0 = (fq * 16) ^ xsw;
  const int x1 = (64 + fq * 16) ^ xsw;
  char* const pA0 = Lb + (wr0 + fr) * 128 + x0;
  char* const pA1 = Lb + (wr0 + fr) * 128 + x1;
  char* const pB0 = Lb + 65536 + (wc0 + fr) * 128 + x0;
  char* const pB1 = Lb + 65536 + (wc0 + fr) * 128 + x1;

  // ---- hoisted staging bases
  const f16* aBase[4]; const f16* wBase[4];
#pragma unroll
  for (int l = 0; l < 4; ++l) {
    const int row = l * 64 + sr;
    const int c2 = scb ^ ((row & 7) << 4);
    aBase[l] = Ap + (size_t)(bm0 + row) * lda + (c2 >> 1);
    wBase[l] = Wp + (size_t)(bn0 + row) * K + (c2 >> 1);
  }

  auto STAGE = [&](int slot, int kt) {
    const int koff = kt * 64;
#pragma unroll
    for (int l = 0; l < 4; ++l)
      gload16(aBase[l] + koff, Lb + slot * 32768 + l * 8192 + tid * 16);
#pragma unroll
    for (int l = 0; l < 4; ++l)
      gload16(wBase[l] + koff, Lb + 65536 + slot * 32768 + l * 8192 + tid * 16);
  };

  STAGE(0, 0);
  STAGE(1, 1);
  VMW8();          // tile 0 landed; tile 1's 8 loads stay in flight
  BARRIER();
  SCHED0();

#pragma unroll 2
  for (int kt = 0; kt < NT; ++kt) {
    const int slot = kt & 1;                 // compile-time under unroll-2
    const int so = slot * 32768;

    f16x8 b[4][2];
#pragma unroll
    for (int nf = 0; nf < 4; ++nf) {
      b[nf][0] = *(const f16x8*)(pB0 + so + nf * 2048);
      b[nf][1] = *(const f16x8*)(pB1 + so + nf * 2048);
    }
    f16x8 a0[2][2], a1[2][2];
#pragma unroll
    for (int i = 0; i < 2; ++i) {
      a0[i][0] = *(const f16x8*)(pA0 + so + i * 2048);
      a0[i][1] = *(const f16x8*)(pA1 + so + i * 2048);
    }

    auto QUAD = [&](int mbase, f16x8 (&a)[2][2]) {
      __builtin_amdgcn_s_setprio(1);
#pragma unroll
      for (int nf = 0; nf < 4; ++nf) {
        acc[mbase][nf]     = MFMA16(a[0][0], b[nf][0], acc[mbase][nf]);
        acc[mbase][nf]     = MFMA16(a[0][1], b[nf][1], acc[mbase][nf]);
        acc[mbase + 1][nf] = MFMA16(a[1][0], b[nf][0], acc[mbase + 1][nf]);
        acc[mbase + 1][nf] = MFMA16(a[1][1], b[nf][1], acc[mbase + 1][nf]);
      }
      __builtin_amdgcn_s_setprio(0);
    };

    // quadrant pipeline: read next A-pair while MFMAing current (reg-only)
#pragma unroll
    for (int i = 0; i < 2; ++i) {
      a1[i][0] = *(const f16x8*)(pA0 + so + (2 + i) * 2048);
      a1[i][1] = *(const f16x8*)(pA1 + so + (2 + i) * 2048);
    }
    QUAD(0, a0);
#pragma unroll
    for (int i = 0; i < 2; ++i) {
      a0[i][0] = *(const f16x8*)(pA0 + so + (4 + i) * 2048);
      a0[i][1] = *(const f16x8*)(pA1 + so + (4 + i) * 2048);
    }
    QUAD(2, a1);
#pragma unroll
    for (int i = 0; i < 2; ++i) {
      a1[i][0] = *(const f16x8*)(pA0 + so + (6 + i) * 2048);
      a1[i][1] = *(const f16x8*)(pA1 + so + (6 + i) * 2048);
    }
    QUAD(4, a0);
    QUAD(6, a1);

    LGKM0();        // all reads of this slot complete
    BARRIER();      // ... in every wave
    SCHED0();
    if (kt + 2 < NT) {
      STAGE(slot, kt + 2);   // overwrite now-dead slot; stays in flight
      SCHED0();
      VMW8();                // tile kt+1 landed (kt+2's 8 still flying)
    } else if (kt + 1 < NT) {
      VMW0();
    }
    BARRIER();
    SCHED0();
  }

#pragma unroll
  for (int nf = 0; nf < 4; ++nf) {
    const int col = bn0 + wc0 + nf * 16 + fr;
    const float bv = bias[col];
#pragma unroll
    for (int m = 0; m < 8; ++m) {
      const int row0 = bm0 + wr0 + m * 16 + fq * 4;
#pragma unroll
      for (int r = 0; r < 4; ++r) {
        float v = fmaxf(acc[m][nf][r] + bv, 0.f);
        C[(size_t)(row0 + r) * ldc + col] = (f16)v;
      }
    }
  }
}

// ---------------------------------------------------------------------------
// Heads: mean = h12@Wm^T + bm ; log_std = clip(h22@Wls^T + bls, -20, 2). fp32 out.
// ---------------------------------------------------------------------------
__global__ __launch_bounds__(256) void head_kernel(
    const f16* __restrict__ H1, const f16* __restrict__ H2,
    const f16* __restrict__ Wm, const float* __restrict__ bm,
    const f16* __restrict__ Wls, const float* __restrict__ bls,
    float* __restrict__ OUT, int M, int K)
{
  const int tid = threadIdx.x, wid = tid >> 6, lane = tid & 63;
  const int m0 = blockIdx.x * 64 + wid * 16;
  const int kb = (lane >> 4) * 8, fr = lane & 15, fq = lane >> 4;

  f32x4 a1[2] = {}, a2[2] = {};
  for (int k0 = 0; k0 < K; k0 += 32) {
    f16x8 f1 = *(const f16x8*)&H1[(size_t)(m0 + fr) * K + k0 + kb];
    f16x8 f2 = *(const f16x8*)&H2[(size_t)(m0 + fr) * K + k0 + kb];
#pragma unroll
    for (int n = 0; n < 2; ++n) {
      f16x8 wm = *(const f16x8*)&Wm[(size_t)(n * 16 + fr) * K + k0 + kb];
      f16x8 wl = *(const f16x8*)&Wls[(size_t)(n * 16 + fr) * K + k0 + kb];
      a1[n] = MFMA16(f1, wm, a1[n]);
      a2[n] = MFMA16(f2, wl, a2[n]);
    }
  }

#pragma unroll
  for (int n = 0; n < 2; ++n) {
    const int col = n * 16 + fr;
    const float bvm = bm[col];
    const float bvl = bls[col];
#pragma unroll
    for (int r = 0; r < 4; ++r) {
      const int row = m0 + fq * 4 + r;
      OUT[(size_t)row * 32 + col] = a1[n][r] + bvm;
      float lv = a2[n][r] + bvl;
      OUT[(size_t)M * 32 + (size_t)row * 32 + col] = fminf(fmaxf(lv, -20.f), 2.f);
    }
  }
}

// ---------------------------------------------------------------------------
extern "C" void kernel_launch(void* const* d_in, const int* in_sizes, int n_in,
                              void* d_out, int out_size, void* d_ws, size_t ws_size,
                              hipStream_t stream) {
  const float* state = (const float*)d_in[0];
  const float* W_lif = (const float*)d_in[1];
  const float* b_lif = (const float*)d_in[2];
  const float* W11   = (const float*)d_in[3];
  const float* b11   = (const float*)d_in[4];
  const float* W12   = (const float*)d_in[5];
  const float* b12   = (const float*)d_in[6];
  const float* W21   = (const float*)d_in[7];
  const float* b21   = (const float*)d_in[8];
  const float* W22   = (const float*)d_in[9];
  const float* b22   = (const float*)d_in[10];
  const float* Wm    = (const float*)d_in[11];
  const float* bm    = (const float*)d_in[12];
  const float* Wls   = (const float*)d_in[13];
  const float* bls   = (const float*)d_in[14];
  float* out = (float*)d_out;

  const int B = 4096, IN = 512, H = 2048;
  char* ws = (char*)d_ws;
  // layout (bytes), peak 80.0 MB:
  f16* x    = (f16*)(ws);
  f16* h1   = (f16*)(ws + 16777216);
  f16* h2   = (f16*)(ws + 33554432);
  f16* s16  = (f16*)(ws + 50331648);
  f16* wl16 = (f16*)(ws + 71303168);
  f16* w4   = (f16*)(ws + 50331648);           // w11h|w21h|w12h|w22h contiguous
  f16* w11h = (f16*)(ws + 50331648);
  f16* w21h = (f16*)(ws + 58720256);
  f16* w12h = (f16*)(ws + 67108864);
  f16* w22h = (f16*)(ws + 75497472);
  f16* h22  = (f16*)(ws + 50331648);
  f16* wmh  = (f16*)(ws + 67108864);           // over w12h (dead after trunk2)
  f16* wlsh = (f16*)(ws + 67239936);
  f16* h12  = x;

  // 1) converts for LIF (state + W_lif in one dispatch)
  const int n8s = B * 5 * IN / 8, n8w = H * IN / 8;
  cvt2b_kernel<<<(n8s + n8w + 255) / 256, 256, 0, stream>>>(
      state, s16, n8s, W_lif, wl16, n8w);

  // 2) fused fc-GEMM + LIF -> x
  lif256_kernel<<<512, 512, 0, stream>>>(s16, wl16, b_lif, x);

  // 3) all four trunk weights -> contiguous fp16 (over s16, dead now)
  cvt4_kernel<<<4 * 524288 / 256, 256, 0, stream>>>(W11, W21, W12, W22, w4);

  // 4) trunk layer-1 (fused dual-output), then layer-2
  trunk256_kernel<<<256, 512, 0, stream>>>(x, x, H, w11h, w21h, b11, b21,
                                           h1, h2, H, 16, 8, H);
  trunk256_kernel<<<256, 512, 0, stream>>>(h1, h2, H, w12h, w22h, b12, b22,
                                           h12, h22, H, 16, 8, H);

  // 5) heads -> d_out = [mean | log_std] fp32
  cvt2_kernel<<<2 * (32 * H / 8) / 256, 256, 0, stream>>>(Wm, Wls, wmh, wlsh, 32 * H / 8);
  head_kernel<<<B / 64, 256, 0, stream>>>(h12, h22, wmh, bm, wlsh, bls, out, B, H);
}

// Round 12
// 264.957 us; speedup vs baseline: 1.1578x; 1.0161x over previous
//
#include <hip/hip_runtime.h>
#include <hip/hip_bf16.h>

// GaussianPolicy: SNN-LIF frontend + 2-branch MLP heads.
// B=4096, IN=512, H=2048, A=32. fp32 in/out; fp16 MFMA compute internally.
// Trunk: 256x256/BK64, XOR-swizzled LDS, QUAD schedule with B-early-free
// per-phase staging interleave, counted vmcnt. LIF: 3-slot ring (proven R11).

typedef _Float16 f16;
using f32x4 = __attribute__((ext_vector_type(4))) float;
using f16x8 = __attribute__((ext_vector_type(8))) f16;   // 8 fp16 = 4 VGPRs

#define MFMA16(a, b, c) __builtin_amdgcn_mfma_f32_16x16x32_f16((a), (b), (c), 0, 0, 0)
#define VMW8()  asm volatile("s_waitcnt vmcnt(8)" ::: "memory")
#define VMW4()  asm volatile("s_waitcnt vmcnt(4)" ::: "memory")
#define VMW0()  asm volatile("s_waitcnt vmcnt(0)" ::: "memory")
#define LGKM0() asm volatile("s_waitcnt lgkmcnt(0)" ::: "memory")
#define BARRIER() __builtin_amdgcn_s_barrier()
#define SCHED0() __builtin_amdgcn_sched_barrier(0)

__device__ __forceinline__ void gload16(const void* g, void* l) {
  // async global->LDS, 16B/lane; LDS dest = wave-uniform base + lane*16
  __builtin_amdgcn_global_load_lds(
      (const __attribute__((address_space(1))) unsigned int*)g,
      (__attribute__((address_space(3))) unsigned int*)l, 16, 0, 0);
}

__device__ __forceinline__ void cvt8(const float4& a, const float4& b, f16* dst) {
  f16x8 d;
  d[0] = (f16)a.x; d[1] = (f16)a.y; d[2] = (f16)a.z; d[3] = (f16)a.w;
  d[4] = (f16)b.x; d[5] = (f16)b.y; d[6] = (f16)b.z; d[7] = (f16)b.w;
  *(f16x8*)dst = d;
}

// ---------------------------------------------------------------------------
// two tensors (unequal sizes) in one dispatch
// ---------------------------------------------------------------------------
__global__ __launch_bounds__(256) void cvt2b_kernel(
    const float* __restrict__ s0, f16* __restrict__ d0, int n8a,
    const float* __restrict__ s1, f16* __restrict__ d1, int n8b)
{
  int i = blockIdx.x * 256 + threadIdx.x;
  const float* src; f16* dst; int k;
  if (i < n8a) { src = s0; dst = d0; k = i; }
  else { k = i - n8a; if (k >= n8b) return; src = s1; dst = d1; }
  const float4* s4 = (const float4*)src;
  float4 a = s4[(size_t)k * 2], b = s4[(size_t)k * 2 + 1];
  cvt8(a, b, dst + (size_t)k * 8);
}

// 4 equal 2^19-n8 tensors -> one contiguous fp16 destination
__global__ __launch_bounds__(256) void cvt4_kernel(
    const float* __restrict__ w0, const float* __restrict__ w1,
    const float* __restrict__ w2, const float* __restrict__ w3,
    f16* __restrict__ dst)
{
  int i = blockIdx.x * 256 + threadIdx.x;     // [0, 4*524288)
  int which = i >> 19, k = i & 524287;
  const float* src = (which == 0) ? w0 : (which == 1) ? w1 : (which == 2) ? w2 : w3;
  const float4* s4 = (const float4*)src;
  float4 a = s4[(size_t)k * 2], b = s4[(size_t)k * 2 + 1];
  cvt8(a, b, dst + (size_t)i * 8);
}

// two equal-size tensors in one dispatch (heads)
__global__ __launch_bounds__(256) void cvt2_kernel(
    const float* __restrict__ s0, const float* __restrict__ s1,
    f16* __restrict__ d0, f16* __restrict__ d1, int n8each)
{
  int i = blockIdx.x * 256 + threadIdx.x;
  const float* src = (i < n8each) ? s0 : s1;
  f16* dst = (i < n8each) ? d0 : d1;
  int k = (i < n8each) ? i : i - n8each;
  if (k >= n8each) return;
  const float4* s4 = (const float4*)src;
  float4 a = s4[(size_t)k * 2], b = s4[(size_t)k * 2 + 1];
  cvt8(a, b, dst + (size_t)k * 8);
}

// ---------------------------------------------------------------------------
// LIF kernel (proven R11). Tile 128x128, BK=64, 8 waves, wave 64x32;
// 5 s-slices sequential; 3-slot LDS ring, stage-at-top, one barrier/iter.
// ---------------------------------------------------------------------------
__global__ __launch_bounds__(512, 1) void lif256_kernel(
    const f16* __restrict__ S,    // [4096*5, 512] fp16 (row (b*5+s))
    const f16* __restrict__ W,    // [2048, 512] fp16
    const float* __restrict__ bl, // [2048] fp32
    f16* __restrict__ X)          // [4096, 2048] fp16
{
  __shared__ alignas(16) f16 lds[6][128 * 64];   // [0..2]=A ring, [3..5]=B ring

  const int tid = threadIdx.x, wid = tid >> 6, lane = tid & 63;
  const int wg = ((int)blockIdx.x % 8) * 64 + (int)blockIdx.x / 8;
  const int bn = wg & 15, bm = wg >> 4;          // nbn=16, nbm=32
  const int b0 = bm * 128, h0 = bn * 128;
  const int wr0 = (wid >> 2) * 64, wc0 = (wid & 3) * 32;
  const int fr = lane & 15, fq = lane >> 4;
  const int sr = tid >> 3, scb = (tid & 7) * 16;  // staging row-in-64, col byte

  f32x4 acc[4][2] = {};
  float mem[4][2][4] = {};
  float cnt[4][2][4] = {};

  // hoisted LDS read bases (BYTES, row stride 128 B)
  char* Lb = (char*)&lds[0][0];
  const int xsw = (fr & 7) << 4;
  const int x0 = (fq * 16) ^ xsw;
  const int x1 = (64 + fq * 16) ^ xsw;
  char* const pA0 = Lb + (wr0 + fr) * 128 + x0;
  char* const pA1 = Lb + (wr0 + fr) * 128 + x1;
  char* const pB0 = Lb + 49152 + (wc0 + fr) * 128 + x0;
  char* const pB1 = Lb + 49152 + (wc0 + fr) * 128 + x1;

  // hoisted staging bases
  const f16* sBase[2]; const f16* wBase[2];
#pragma unroll
  for (int l = 0; l < 2; ++l) {
    const int row = l * 64 + sr;
    const int c2 = scb ^ ((row & 7) << 4);
    sBase[l] = S + (size_t)(b0 + row) * 2560 + (c2 >> 1);
    wBase[l] = W + (size_t)(h0 + row) * 512 + (c2 >> 1);
  }

  auto STAGE = [&](int soSt, int g) {
    const int koff = (g >> 3) * 512 + (g & 7) * 64;
    const int kw = (g & 7) * 64;
#pragma unroll
    for (int l = 0; l < 2; ++l)
      gload16(sBase[l] + koff, Lb + soSt + l * 8192 + tid * 16);
#pragma unroll
    for (int l = 0; l < 2; ++l)
      gload16(wBase[l] + kw, Lb + 49152 + soSt + l * 8192 + tid * 16);
  };

  const float bias[2] = { bl[h0 + wc0 + fr], bl[h0 + wc0 + 16 + fr] };

  STAGE(0, 0);
  STAGE(16384, 1);
  VMW4();
  BARRIER();
  SCHED0();

  int soRead = 0, soStage = 32768;
  for (int g = 0; g < 40; ++g) {
    if (g + 2 < 40) STAGE(soStage, g + 2);
    SCHED0();

    f16x8 b[2][2], a0[2][2], a1[2][2];
#pragma unroll
    for (int nf = 0; nf < 2; ++nf) {
      b[nf][0] = *(const f16x8*)(pB0 + soRead + nf * 2048);
      b[nf][1] = *(const f16x8*)(pB1 + soRead + nf * 2048);
    }
#pragma unroll
    for (int i = 0; i < 2; ++i) {
      a0[i][0] = *(const f16x8*)(pA0 + soRead + i * 2048);
      a0[i][1] = *(const f16x8*)(pA1 + soRead + i * 2048);
      a1[i][0] = *(const f16x8*)(pA0 + soRead + (2 + i) * 2048);
      a1[i][1] = *(const f16x8*)(pA1 + soRead + (2 + i) * 2048);
    }

    __builtin_amdgcn_s_setprio(1);
#pragma unroll
    for (int i = 0; i < 2; ++i)
#pragma unroll
      for (int nf = 0; nf < 2; ++nf) {
        acc[i][nf] = MFMA16(a0[i][0], b[nf][0], acc[i][nf]);
        acc[i][nf] = MFMA16(a0[i][1], b[nf][1], acc[i][nf]);
      }
#pragma unroll
    for (int i = 0; i < 2; ++i)
#pragma unroll
      for (int nf = 0; nf < 2; ++nf) {
        acc[2 + i][nf] = MFMA16(a1[i][0], b[nf][0], acc[2 + i][nf]);
        acc[2 + i][nf] = MFMA16(a1[i][1], b[nf][1], acc[2 + i][nf]);
      }
    __builtin_amdgcn_s_setprio(0);

    if ((g & 7) == 7) {
#pragma unroll
      for (int mf = 0; mf < 4; ++mf)
#pragma unroll
        for (int nf = 0; nf < 2; ++nf) {
#pragma unroll
          for (int r = 0; r < 4; ++r) {
            const float fc = acc[mf][nf][r] + bias[nf];
            float m = mem[mf][nf][r], c = cnt[mf][nf][r];
#pragma unroll
            for (int j = 0; j < 3; ++j) {
              m = ((m > 0.2f) ? 0.f : m * 0.2f) + fc;   // DECAY=0.2, spike resets
              c += (m > 0.2f) ? 1.f : 0.f;              // THRESH=0.2
            }
            mem[mf][nf][r] = m; cnt[mf][nf][r] = c;
          }
          acc[mf][nf] = f32x4{0.f, 0.f, 0.f, 0.f};
        }
    }

    LGKM0();
    if (g + 2 < 40)      { VMW4(); }
    else if (g + 1 < 40) { VMW0(); }
    BARRIER();
    SCHED0();

    soRead  = (soRead  == 32768) ? 0 : soRead  + 16384;
    soStage = (soStage == 32768) ? 0 : soStage + 16384;
  }

#pragma unroll
  for (int nf = 0; nf < 2; ++nf) {
    const int col = h0 + wc0 + nf * 16 + fr;
#pragma unroll
    for (int mf = 0; mf < 4; ++mf) {
      const int row0 = b0 + wr0 + mf * 16 + fq * 4;
#pragma unroll
      for (int r = 0; r < 4; ++r)
        X[(size_t)(row0 + r) * 2048 + col] = (f16)(cnt[mf][nf][r] / 15.0f);
    }
  }
}

// ---------------------------------------------------------------------------
// Trunk GEMM: C = relu(A @ W^T + bias), fp16 in/out, fp32 bias/accum.
// 256x256 tile, BK=64, 8 waves (2Mx4N), wave 128x64 = 8x4 frags.
// B-early-free schedule: all B reads in phase 0 -> lgkm0+barrier -> B-slot is
// dead -> stage kt+2's B there (3 quadrants early). A-slot dies after q3's
// reads -> stage kt+2's A before the last QUAD. vmcnt(8) never drains mid-loop.
// ---------------------------------------------------------------------------
__global__ __launch_bounds__(512, 2) void trunk256_kernel(
    const f16* __restrict__ A0, const f16* __restrict__ A1, int lda,
    const f16* __restrict__ W0, const f16* __restrict__ W1,
    const float* __restrict__ bb0, const float* __restrict__ bb1,
    f16* __restrict__ C0, f16* __restrict__ C1, int ldc,
    int nbm, int nbn_half, int K)
{
  __shared__ alignas(16) f16 lds[4][256 * 64];   // [0,1]=A slots, [2,3]=B slots

  const int tid = threadIdx.x, wid = tid >> 6, lane = tid & 63;
  const int nwg = nbm * nbn_half * 2, q8 = nwg / 8;
  const int wg = ((int)blockIdx.x % 8) * q8 + (int)blockIdx.x / 8;
  const int bmi = wg % nbm, t = wg / nbm;
  const int half = (t >= nbn_half);
  const f16* Ap = half ? A1 : A0;
  const f16* Wp = half ? W1 : W0;
  const float* bias = half ? bb1 : bb0;
  f16* C = half ? C1 : C0;
  const int bm0 = bmi * 256;
  const int bn0 = (half ? t - nbn_half : t) * 256;

  const int wr0 = (wid >> 2) * 128, wc0 = (wid & 3) * 64;
  const int fr = lane & 15, fq = lane >> 4;
  const int sr = tid >> 3, scb = (tid & 7) * 16;

  f32x4 acc[8][4] = {};
  const int NT = K / 64;

  // hoisted LDS read bases (BYTES, row stride 128 B)
  char* Lb = (char*)&lds[0][0];
  const int xsw = (fr & 7) << 4;
  const int x0 = (fq * 16) ^ xsw;
  const int x1 = (64 + fq * 16) ^ xsw;
  char* const pA0 = Lb + (wr0 + fr) * 128 + x0;
  char* const pA1 = Lb + (wr0 + fr) * 128 + x1;
  char* const pB0 = Lb + 65536 + (wc0 + fr) * 128 + x0;
  char* const pB1 = Lb + 65536 + (wc0 + fr) * 128 + x1;

  // hoisted staging bases
  const f16* aBase[4]; const f16* wBase[4];
#pragma unroll
  for (int l = 0; l < 4; ++l) {
    const int row = l * 64 + sr;
    const int c2 = scb ^ ((row & 7) << 4);
    aBase[l] = Ap + (size_t)(bm0 + row) * lda + (c2 >> 1);
    wBase[l] = Wp + (size_t)(bn0 + row) * K + (c2 >> 1);
  }

  auto STAGE_A = [&](int slot, int kt) {
    const int koff = kt * 64;
#pragma unroll
    for (int l = 0; l < 4; ++l)
      gload16(aBase[l] + koff, Lb + slot * 32768 + l * 8192 + tid * 16);
  };
  auto STAGE_B = [&](int slot, int kt) {
    const int koff = kt * 64;
#pragma unroll
    for (int l = 0; l < 4; ++l)
      gload16(wBase[l] + koff, Lb + 65536 + slot * 32768 + l * 8192 + tid * 16);
  };

  STAGE_A(0, 0); STAGE_B(0, 0);
  STAGE_A(1, 1); STAGE_B(1, 1);
  VMW8();          // tile 0 landed; tile 1's 8 loads stay in flight
  BARRIER();
  SCHED0();

#pragma unroll 2
  for (int kt = 0; kt < NT; ++kt) {
    const int slot = kt & 1;                 // compile-time under unroll-2
    const int so = slot * 32768;

    auto QUAD = [&](int mbase, f16x8 (&b)[4][2], f16x8 (&a)[2][2]) {
      __builtin_amdgcn_s_setprio(1);
#pragma unroll
      for (int nf = 0; nf < 4; ++nf) {
        acc[mbase][nf]     = MFMA16(a[0][0], b[nf][0], acc[mbase][nf]);
        acc[mbase][nf]     = MFMA16(a[0][1], b[nf][1], acc[mbase][nf]);
        acc[mbase + 1][nf] = MFMA16(a[1][0], b[nf][0], acc[mbase + 1][nf]);
        acc[mbase + 1][nf] = MFMA16(a[1][1], b[nf][1], acc[mbase + 1][nf]);
      }
      __builtin_amdgcn_s_setprio(0);
    };

    // ---- P0: B (8 reads) + A quad0 (4 reads); B-slot freed after barrier
    f16x8 b[4][2], a0[2][2], a1[2][2];
#pragma unroll
    for (int nf = 0; nf < 4; ++nf) {
      b[nf][0] = *(const f16x8*)(pB0 + so + nf * 2048);
      b[nf][1] = *(const f16x8*)(pB1 + so + nf * 2048);
    }
#pragma unroll
    for (int i = 0; i < 2; ++i) {
      a0[i][0] = *(const f16x8*)(pA0 + so + i * 2048);
      a0[i][1] = *(const f16x8*)(pA1 + so + i * 2048);
    }
    LGKM0();
    BARRIER();                    // all waves' B (and q0) reads retired
    if (kt + 2 < NT) STAGE_B(slot, kt + 2);   // prefetch into dead B-slot
    SCHED0();

    // q1 reads overlap QUAD0 (reg-only MFMA)
#pragma unroll
    for (int i = 0; i < 2; ++i) {
      a1[i][0] = *(const f16x8*)(pA0 + so + (2 + i) * 2048);
      a1[i][1] = *(const f16x8*)(pA1 + so + (2 + i) * 2048);
    }
    QUAD(0, b, a0);
    LGKM0(); SCHED0();
#pragma unroll
    for (int i = 0; i < 2; ++i) {
      a0[i][0] = *(const f16x8*)(pA0 + so + (4 + i) * 2048);
      a0[i][1] = *(const f16x8*)(pA1 + so + (4 + i) * 2048);
    }
    QUAD(2, b, a1);
    LGKM0(); SCHED0();
#pragma unroll
    for (int i = 0; i < 2; ++i) {
      a1[i][0] = *(const f16x8*)(pA0 + so + (6 + i) * 2048);
      a1[i][1] = *(const f16x8*)(pA1 + so + (6 + i) * 2048);
    }
    QUAD(4, b, a0);
    LGKM0();                      // q3 reads retired -> all A reads done
    BARRIER();                    // A-slot dead block-wide
    if (kt + 2 < NT) STAGE_A(slot, kt + 2);
    SCHED0();
    QUAD(6, b, a1);
    if (kt + 2 < NT)      { VMW8(); }   // tile kt+1 landed (kt+2's 8 flying)
    else if (kt + 1 < NT) { VMW0(); }
    BARRIER();
    SCHED0();
  }

#pragma unroll
  for (int nf = 0; nf < 4; ++nf) {
    const int col = bn0 + wc0 + nf * 16 + fr;
    const float bv = bias[col];
#pragma unroll
    for (int m = 0; m < 8; ++m) {
      const int row0 = bm0 + wr0 + m * 16 + fq * 4;
#pragma unroll
      for (int r = 0; r < 4; ++r) {
        float v = fmaxf(acc[m][nf][r] + bv, 0.f);
        C[(size_t)(row0 + r) * ldc + col] = (f16)v;
      }
    }
  }
}

// ---------------------------------------------------------------------------
// Heads: mean = h12@Wm^T + bm ; log_std = clip(h22@Wls^T + bls, -20, 2). fp32 out.
// ---------------------------------------------------------------------------
__global__ __launch_bounds__(256) void head_kernel(
    const f16* __restrict__ H1, const f16* __restrict__ H2,
    const f16* __restrict__ Wm, const float* __restrict__ bm,
    const f16* __restrict__ Wls, const float* __restrict__ bls,
    float* __restrict__ OUT, int M, int K)
{
  const int tid = threadIdx.x, wid = tid >> 6, lane = tid & 63;
  const int m0 = blockIdx.x * 64 + wid * 16;
  const int kb = (lane >> 4) * 8, fr = lane & 15, fq = lane >> 4;

  f32x4 a1[2] = {}, a2[2] = {};
  for (int k0 = 0; k0 < K; k0 += 32) {
    f16x8 f1 = *(const f16x8*)&H1[(size_t)(m0 + fr) * K + k0 + kb];
    f16x8 f2 = *(const f16x8*)&H2[(size_t)(m0 + fr) * K + k0 + kb];
#pragma unroll
    for (int n = 0; n < 2; ++n) {
      f16x8 wm = *(const f16x8*)&Wm[(size_t)(n * 16 + fr) * K + k0 + kb];
      f16x8 wl = *(const f16x8*)&Wls[(size_t)(n * 16 + fr) * K + k0 + kb];
      a1[n] = MFMA16(f1, wm, a1[n]);
      a2[n] = MFMA16(f2, wl, a2[n]);
    }
  }

#pragma unroll
  for (int n = 0; n < 2; ++n) {
    const int col = n * 16 + fr;
    const float bvm = bm[col];
    const float bvl = bls[col];
#pragma unroll
    for (int r = 0; r < 4; ++r) {
      const int row = m0 + fq * 4 + r;
      OUT[(size_t)row * 32 + col] = a1[n][r] + bvm;
      float lv = a2[n][r] + bvl;
      OUT[(size_t)M * 32 + (size_t)row * 32 + col] = fminf(fmaxf(lv, -20.f), 2.f);
    }
  }
}

// ---------------------------------------------------------------------------
extern "C" void kernel_launch(void* const* d_in, const int* in_sizes, int n_in,
                              void* d_out, int out_size, void* d_ws, size_t ws_size,
                              hipStream_t stream) {
  const float* state = (const float*)d_in[0];
  const float* W_lif = (const float*)d_in[1];
  const float* b_lif = (const float*)d_in[2];
  const float* W11   = (const float*)d_in[3];
  const float* b11   = (const float*)d_in[4];
  const float* W12   = (const float*)d_in[5];
  const float* b12   = (const float*)d_in[6];
  const float* W21   = (const float*)d_in[7];
  const float* b21   = (const float*)d_in[8];
  const float* W22   = (const float*)d_in[9];
  const float* b22   = (const float*)d_in[10];
  const float* Wm    = (const float*)d_in[11];
  const float* bm    = (const float*)d_in[12];
  const float* Wls   = (const float*)d_in[13];
  const float* bls   = (const float*)d_in[14];
  float* out = (float*)d_out;

  const int B = 4096, IN = 512, H = 2048;
  char* ws = (char*)d_ws;
  // layout (bytes), peak 80.0 MB:
  f16* x    = (f16*)(ws);
  f16* h1   = (f16*)(ws + 16777216);
  f16* h2   = (f16*)(ws + 33554432);
  f16* s16  = (f16*)(ws + 50331648);
  f16* wl16 = (f16*)(ws + 71303168);
  f16* w4   = (f16*)(ws + 50331648);           // w11h|w21h|w12h|w22h contiguous
  f16* w11h = (f16*)(ws + 50331648);
  f16* w21h = (f16*)(ws + 58720256);
  f16* w12h = (f16*)(ws + 67108864);
  f16* w22h = (f16*)(ws + 75497472);
  f16* h22  = (f16*)(ws + 50331648);
  f16* wmh  = (f16*)(ws + 67108864);           // over w12h (dead after trunk2)
  f16* wlsh = (f16*)(ws + 67239936);
  f16* h12  = x;

  // 1) converts for LIF (state + W_lif in one dispatch)
  const int n8s = B * 5 * IN / 8, n8w = H * IN / 8;
  cvt2b_kernel<<<(n8s + n8w + 255) / 256, 256, 0, stream>>>(
      state, s16, n8s, W_lif, wl16, n8w);

  // 2) fused fc-GEMM + LIF -> x
  lif256_kernel<<<512, 512, 0, stream>>>(s16, wl16, b_lif, x);

  // 3) all four trunk weights -> contiguous fp16 (over s16, dead now)
  cvt4_kernel<<<4 * 524288 / 256, 256, 0, stream>>>(W11, W21, W12, W22, w4);

  // 4) trunk layer-1 (fused dual-output), then layer-2
  trunk256_kernel<<<256, 512, 0, stream>>>(x, x, H, w11h, w21h, b11, b21,
                                           h1, h2, H, 16, 8, H);
  trunk256_kernel<<<256, 512, 0, stream>>>(h1, h2, H, w12h, w22h, b12, b22,
                                           h12, h22, H, 16, 8, H);

  // 5) heads -> d_out = [mean | log_std] fp32
  cvt2_kernel<<<2 * (32 * H / 8) / 256, 256, 0, stream>>>(Wm, Wls, wmh, wlsh, 32 * H / 8);
  head_kernel<<<B / 64, 256, 0, stream>>>(h12, h22, wmh, bm, wlsh, bls, out, B, H);
}

// Round 13
// 259.810 us; speedup vs baseline: 1.1807x; 1.0198x over previous
//
#include <hip/hip_runtime.h>
#include <hip/hip_bf16.h>

// GaussianPolicy: SNN-LIF frontend + 2-branch MLP heads.
// B=4096, IN=512, H=2048, A=32. fp32 in/out; fp16 MFMA compute internally.
// Trunk: 256x256/BK64, XOR-swizzled LDS, B-early-free QUAD schedule (R12).
// LIF: 256x128 tile, 8 waves (4Mx2N), wave 64x64, ring-3 LDS, one barrier/iter.

typedef _Float16 f16;
using f32x4 = __attribute__((ext_vector_type(4))) float;
using f16x8 = __attribute__((ext_vector_type(8))) f16;   // 8 fp16 = 4 VGPRs

#define MFMA16(a, b, c) __builtin_amdgcn_mfma_f32_16x16x32_f16((a), (b), (c), 0, 0, 0)
#define VMW8()  asm volatile("s_waitcnt vmcnt(8)" ::: "memory")
#define VMW6()  asm volatile("s_waitcnt vmcnt(6)" ::: "memory")
#define VMW0()  asm volatile("s_waitcnt vmcnt(0)" ::: "memory")
#define LGKM0() asm volatile("s_waitcnt lgkmcnt(0)" ::: "memory")
#define BARRIER() __builtin_amdgcn_s_barrier()
#define SCHED0() __builtin_amdgcn_sched_barrier(0)

__device__ __forceinline__ void gload16(const void* g, void* l) {
  // async global->LDS, 16B/lane; LDS dest = wave-uniform base + lane*16
  __builtin_amdgcn_global_load_lds(
      (const __attribute__((address_space(1))) unsigned int*)g,
      (__attribute__((address_space(3))) unsigned int*)l, 16, 0, 0);
}

__device__ __forceinline__ void cvt8(const float4& a, const float4& b, f16* dst) {
  f16x8 d;
  d[0] = (f16)a.x; d[1] = (f16)a.y; d[2] = (f16)a.z; d[3] = (f16)a.w;
  d[4] = (f16)b.x; d[5] = (f16)b.y; d[6] = (f16)b.z; d[7] = (f16)b.w;
  *(f16x8*)dst = d;
}

// ---------------------------------------------------------------------------
// two tensors (unequal sizes) in one dispatch
// ---------------------------------------------------------------------------
__global__ __launch_bounds__(256) void cvt2b_kernel(
    const float* __restrict__ s0, f16* __restrict__ d0, int n8a,
    const float* __restrict__ s1, f16* __restrict__ d1, int n8b)
{
  int i = blockIdx.x * 256 + threadIdx.x;
  const float* src; f16* dst; int k;
  if (i < n8a) { src = s0; dst = d0; k = i; }
  else { k = i - n8a; if (k >= n8b) return; src = s1; dst = d1; }
  const float4* s4 = (const float4*)src;
  float4 a = s4[(size_t)k * 2], b = s4[(size_t)k * 2 + 1];
  cvt8(a, b, dst + (size_t)k * 8);
}

// 4 equal 2^19-n8 tensors -> one contiguous fp16 destination
__global__ __launch_bounds__(256) void cvt4_kernel(
    const float* __restrict__ w0, const float* __restrict__ w1,
    const float* __restrict__ w2, const float* __restrict__ w3,
    f16* __restrict__ dst)
{
  int i = blockIdx.x * 256 + threadIdx.x;     // [0, 4*524288)
  int which = i >> 19, k = i & 524287;
  const float* src = (which == 0) ? w0 : (which == 1) ? w1 : (which == 2) ? w2 : w3;
  const float4* s4 = (const float4*)src;
  float4 a = s4[(size_t)k * 2], b = s4[(size_t)k * 2 + 1];
  cvt8(a, b, dst + (size_t)i * 8);
}

// two equal-size tensors in one dispatch (heads)
__global__ __launch_bounds__(256) void cvt2_kernel(
    const float* __restrict__ s0, const float* __restrict__ s1,
    f16* __restrict__ d0, f16* __restrict__ d1, int n8each)
{
  int i = blockIdx.x * 256 + threadIdx.x;
  const float* src = (i < n8each) ? s0 : s1;
  f16* dst = (i < n8each) ? d0 : d1;
  int k = (i < n8each) ? i : i - n8each;
  if (k >= n8each) return;
  const float4* s4 = (const float4*)src;
  float4 a = s4[(size_t)k * 2], b = s4[(size_t)k * 2 + 1];
  cvt8(a, b, dst + (size_t)k * 8);
}

// ---------------------------------------------------------------------------
// LIF kernel. Tile 256(M=batch) x 128(N=hidden), BK=64, 8 waves (4Mx2N),
// wave 64x64 = 4x4 frags = 32 MFMA per 16 ds_reads (2x better ratio than
// 64x32). 5 s-slices sequential (g in [0,40), s=g>>3); per-thread mem (f32)
// + packed byte counters (u32 per 4 rows). grid 256 = 1 block/CU, 1 round.
// LDS: A ring-3 [256][64] (3x32KB) + B ring-3 [128][64] (3x16KB) = 144KB.
// One barrier/iter; VMW6 counted (6 loads/tile); slot g+2 == slot g-1.
// ---------------------------------------------------------------------------
__global__ __launch_bounds__(512, 1) void lif256_kernel(
    const f16* __restrict__ S,    // [4096*5, 512] fp16 (row (b*5+s))
    const f16* __restrict__ W,    // [2048, 512] fp16
    const float* __restrict__ bl, // [2048] fp32
    f16* __restrict__ X)          // [4096, 2048] fp16
{
  __shared__ alignas(16) f16 lds[73728];         // 144 KB: A@0, B@98304 bytes

  const int tid = threadIdx.x, wid = tid >> 6, lane = tid & 63;
  const int wg = ((int)blockIdx.x % 8) * 32 + (int)blockIdx.x / 8;
  const int bn = wg & 15, bm = wg >> 4;          // nbn=16, nbm=16
  const int b0 = bm * 256, h0 = bn * 128;
  const int wr0 = (wid >> 1) * 64, wc0 = (wid & 1) * 64;
  const int fr = lane & 15, fq = lane >> 4;
  const int sr = tid >> 3, scb = (tid & 7) * 16;  // staging row-in-64, col byte

  f32x4 acc[4][4] = {};
  float mem[4][4][4] = {};
  unsigned pcnt[4][4] = {};                       // byte r of pcnt = spike count

  // hoisted LDS read bases (BYTES, row stride 128 B)
  char* Lb = (char*)&lds[0];
  const int xsw = (fr & 7) << 4;
  const int x0 = (fq * 16) ^ xsw;
  const int x1 = (64 + fq * 16) ^ xsw;
  char* const pA0 = Lb + (wr0 + fr) * 128 + x0;
  char* const pA1 = Lb + (wr0 + fr) * 128 + x1;
  char* const pB0 = Lb + 98304 + (wc0 + fr) * 128 + x0;
  char* const pB1 = Lb + 98304 + (wc0 + fr) * 128 + x1;

  // hoisted staging bases (pre-swizzled source col)
  const f16* sBase[4]; const f16* wBase[2];
#pragma unroll
  for (int l = 0; l < 4; ++l) {
    const int row = l * 64 + sr;
    const int c2 = scb ^ ((row & 7) << 4);
    sBase[l] = S + (size_t)(b0 + row) * 2560 + (c2 >> 1);
  }
#pragma unroll
  for (int l = 0; l < 2; ++l) {
    const int row = l * 64 + sr;
    const int c2 = scb ^ ((row & 7) << 4);
    wBase[l] = W + (size_t)(h0 + row) * 512 + (c2 >> 1);
  }

  // stage tile g: A 4 gloads (8KB each), B 2 gloads
  auto STAGE = [&](int soA, int soB, int g) {
    const int koff = (g >> 3) * 512 + (g & 7) * 64;
    const int kw = (g & 7) * 64;
#pragma unroll
    for (int l = 0; l < 4; ++l)
      gload16(sBase[l] + koff, Lb + soA + l * 8192 + tid * 16);
#pragma unroll
    for (int l = 0; l < 2; ++l)
      gload16(wBase[l] + kw, Lb + 98304 + soB + l * 8192 + tid * 16);
  };

  const float bias[4] = { bl[h0 + wc0 + fr],      bl[h0 + wc0 + 16 + fr],
                          bl[h0 + wc0 + 32 + fr], bl[h0 + wc0 + 48 + fr] };

  STAGE(0, 0, 0);
  STAGE(32768, 16384, 1);
  VMW6();          // tile 0 landed (tile 1's 6 loads in flight)
  BARRIER();
  SCHED0();

  int soA = 0, soB = 0;                  // read offsets (slot g%3)
  int soStA = 65536, soStB = 32768;      // stage offsets (slot (g+2)%3)
  for (int g = 0; g < 40; ++g) {
    if (g + 2 < 40) STAGE(soStA, soStB, g + 2);   // slot drained end of g-1
    SCHED0();

    // 16 ds_reads of slot g%3
    f16x8 b[4][2], a[4][2];
#pragma unroll
    for (int nf = 0; nf < 4; ++nf) {
      b[nf][0] = *(const f16x8*)(pB0 + soB + nf * 2048);
      b[nf][1] = *(const f16x8*)(pB1 + soB + nf * 2048);
    }
#pragma unroll
    for (int mf = 0; mf < 4; ++mf) {
      a[mf][0] = *(const f16x8*)(pA0 + soA + mf * 2048);
      a[mf][1] = *(const f16x8*)(pA1 + soA + mf * 2048);
    }

    __builtin_amdgcn_s_setprio(1);
#pragma unroll
    for (int mf = 0; mf < 4; ++mf)
#pragma unroll
      for (int nf = 0; nf < 4; ++nf) {
        acc[mf][nf] = MFMA16(a[mf][0], b[nf][0], acc[mf][nf]);
        acc[mf][nf] = MFMA16(a[mf][1], b[nf][1], acc[mf][nf]);
      }
    __builtin_amdgcn_s_setprio(0);

    if ((g & 7) == 7) {
      // slice boundary: 3 LIF reps with fc = acc + bias; reset acc
#pragma unroll
      for (int mf = 0; mf < 4; ++mf)
#pragma unroll
        for (int nf = 0; nf < 4; ++nf) {
          unsigned pc = pcnt[mf][nf];
#pragma unroll
          for (int r = 0; r < 4; ++r) {
            const float fc = acc[mf][nf][r] + bias[nf];
            float m = mem[mf][nf][r];
            const unsigned inc = 1u << (8 * r);
#pragma unroll
            for (int j = 0; j < 3; ++j) {
              m = ((m > 0.2f) ? 0.f : m * 0.2f) + fc;   // DECAY=0.2, spike resets
              pc += (m > 0.2f) ? inc : 0u;              // THRESH=0.2
            }
            mem[mf][nf][r] = m;
          }
          pcnt[mf][nf] = pc;
          acc[mf][nf] = f32x4{0.f, 0.f, 0.f, 0.f};
        }
    }

    LGKM0();                              // my reads of this slot done
    if (g + 2 < 40)      { VMW6(); }      // tile g+1 landed (g+2's 6 flying)
    else if (g + 1 < 40) { VMW0(); }
    BARRIER();
    SCHED0();

    soA   = (soA   == 65536) ? 0 : soA   + 32768;
    soB   = (soB   == 32768) ? 0 : soB   + 16384;
    soStA = (soStA == 65536) ? 0 : soStA + 32768;
    soStB = (soStB == 32768) ? 0 : soStB + 16384;
  }

#pragma unroll
  for (int nf = 0; nf < 4; ++nf) {
    const int col = h0 + wc0 + nf * 16 + fr;
#pragma unroll
    for (int mf = 0; mf < 4; ++mf) {
      const int row0 = b0 + wr0 + mf * 16 + fq * 4;
#pragma unroll
      for (int r = 0; r < 4; ++r) {
        const float c = (float)((pcnt[mf][nf] >> (8 * r)) & 255u);
        X[(size_t)(row0 + r) * 2048 + col] = (f16)(c / 15.0f);
      }
    }
  }
}

// ---------------------------------------------------------------------------
// Trunk GEMM: C = relu(A @ W^T + bias), fp16 in/out, fp32 bias/accum.
// 256x256 tile, BK=64, 8 waves (2Mx4N), wave 128x64 = 8x4 frags.
// B-early-free schedule (proven R12). Dual column-halves (fusion).
// ---------------------------------------------------------------------------
__global__ __launch_bounds__(512, 2) void trunk256_kernel(
    const f16* __restrict__ A0, const f16* __restrict__ A1, int lda,
    const f16* __restrict__ W0, const f16* __restrict__ W1,
    const float* __restrict__ bb0, const float* __restrict__ bb1,
    f16* __restrict__ C0, f16* __restrict__ C1, int ldc,
    int nbm, int nbn_half, int K)
{
  __shared__ alignas(16) f16 lds[4][256 * 64];   // [0,1]=A slots, [2,3]=B slots

  const int tid = threadIdx.x, wid = tid >> 6, lane = tid & 63;
  const int nwg = nbm * nbn_half * 2, q8 = nwg / 8;
  const int wg = ((int)blockIdx.x % 8) * q8 + (int)blockIdx.x / 8;
  const int bmi = wg % nbm, t = wg / nbm;
  const int half = (t >= nbn_half);
  const f16* Ap = half ? A1 : A0;
  const f16* Wp = half ? W1 : W0;
  const float* bias = half ? bb1 : bb0;
  f16* C = half ? C1 : C0;
  const int bm0 = bmi * 256;
  const int bn0 = (half ? t - nbn_half : t) * 256;

  const int wr0 = (wid >> 2) * 128, wc0 = (wid & 3) * 64;
  const int fr = lane & 15, fq = lane >> 4;
  const int sr = tid >> 3, scb = (tid & 7) * 16;

  f32x4 acc[8][4] = {};
  const int NT = K / 64;

  // hoisted LDS read bases (BYTES, row stride 128 B)
  char* Lb = (char*)&lds[0][0];
  const int xsw = (fr & 7) << 4;
  const int x0 = (fq * 16) ^ xsw;
  const int x1 = (64 + fq * 16) ^ xsw;
  char* const pA0 = Lb + (wr0 + fr) * 128 + x0;
  char* const pA1 = Lb + (wr0 + fr) * 128 + x1;
  char* const pB0 = Lb + 65536 + (wc0 + fr) * 128 + x0;
  char* const pB1 = Lb + 65536 + (wc0 + fr) * 128 + x1;

  // hoisted staging bases
  const f16* aBase[4]; const f16* wBase[4];
#pragma unroll
  for (int l = 0; l < 4; ++l) {
    const int row = l * 64 + sr;
    const int c2 = scb ^ ((row & 7) << 4);
    aBase[l] = Ap + (size_t)(bm0 + row) * lda + (c2 >> 1);
    wBase[l] = Wp + (size_t)(bn0 + row) * K + (c2 >> 1);
  }

  auto STAGE_A = [&](int slot, int kt) {
    const int koff = kt * 64;
#pragma unroll
    for (int l = 0; l < 4; ++l)
      gload16(aBase[l] + koff, Lb + slot * 32768 + l * 8192 + tid * 16);
  };
  auto STAGE_B = [&](int slot, int kt) {
    const int koff = kt * 64;
#pragma unroll
    for (int l = 0; l < 4; ++l)
      gload16(wBase[l] + koff, Lb + 65536 + slot * 32768 + l * 8192 + tid * 16);
  };

  STAGE_A(0, 0); STAGE_B(0, 0);
  STAGE_A(1, 1); STAGE_B(1, 1);
  VMW8();          // tile 0 landed; tile 1's 8 loads stay in flight
  BARRIER();
  SCHED0();

#pragma unroll 2
  for (int kt = 0; kt < NT; ++kt) {
    const int slot = kt & 1;                 // compile-time under unroll-2
    const int so = slot * 32768;

    auto QUAD = [&](int mbase, f16x8 (&b)[4][2], f16x8 (&a)[2][2]) {
      __builtin_amdgcn_s_setprio(1);
#pragma unroll
      for (int nf = 0; nf < 4; ++nf) {
        acc[mbase][nf]     = MFMA16(a[0][0], b[nf][0], acc[mbase][nf]);
        acc[mbase][nf]     = MFMA16(a[0][1], b[nf][1], acc[mbase][nf]);
        acc[mbase + 1][nf] = MFMA16(a[1][0], b[nf][0], acc[mbase + 1][nf]);
        acc[mbase + 1][nf] = MFMA16(a[1][1], b[nf][1], acc[mbase + 1][nf]);
      }
      __builtin_amdgcn_s_setprio(0);
    };

    // ---- P0: B (8 reads) + A quad0 (4 reads); B-slot freed after barrier
    f16x8 b[4][2], a0[2][2], a1[2][2];
#pragma unroll
    for (int nf = 0; nf < 4; ++nf) {
      b[nf][0] = *(const f16x8*)(pB0 + so + nf * 2048);
      b[nf][1] = *(const f16x8*)(pB1 + so + nf * 2048);
    }
#pragma unroll
    for (int i = 0; i < 2; ++i) {
      a0[i][0] = *(const f16x8*)(pA0 + so + i * 2048);
      a0[i][1] = *(const f16x8*)(pA1 + so + i * 2048);
    }
    LGKM0();
    BARRIER();                    // all waves' B (and q0) reads retired
    if (kt + 2 < NT) STAGE_B(slot, kt + 2);   // prefetch into dead B-slot
    SCHED0();

    // q1 reads overlap QUAD0 (reg-only MFMA)
#pragma unroll
    for (int i = 0; i < 2; ++i) {
      a1[i][0] = *(const f16x8*)(pA0 + so + (2 + i) * 2048);
      a1[i][1] = *(const f16x8*)(pA1 + so + (2 + i) * 2048);
    }
    QUAD(0, b, a0);
    LGKM0(); SCHED0();
#pragma unroll
    for (int i = 0; i < 2; ++i) {
      a0[i][0] = *(const f16x8*)(pA0 + so + (4 + i) * 2048);
      a0[i][1] = *(const f16x8*)(pA1 + so + (4 + i) * 2048);
    }
    QUAD(2, b, a1);
    LGKM0(); SCHED0();
#pragma unroll
    for (int i = 0; i < 2; ++i) {
      a1[i][0] = *(const f16x8*)(pA0 + so + (6 + i) * 2048);
      a1[i][1] = *(const f16x8*)(pA1 + so + (6 + i) * 2048);
    }
    QUAD(4, b, a0);
    LGKM0();                      // q3 reads retired -> all A reads done
    BARRIER();                    // A-slot dead block-wide
    if (kt + 2 < NT) STAGE_A(slot, kt + 2);
    SCHED0();
    QUAD(6, b, a1);
    if (kt + 2 < NT)      { VMW8(); }   // tile kt+1 landed (kt+2's 8 flying)
    else if (kt + 1 < NT) { VMW0(); }
    BARRIER();
    SCHED0();
  }

#pragma unroll
  for (int nf = 0; nf < 4; ++nf) {
    const int col = bn0 + wc0 + nf * 16 + fr;
    const float bv = bias[col];
#pragma unroll
    for (int m = 0; m < 8; ++m) {
      const int row0 = bm0 + wr0 + m * 16 + fq * 4;
#pragma unroll
      for (int r = 0; r < 4; ++r) {
        float v = fmaxf(acc[m][nf][r] + bv, 0.f);
        C[(size_t)(row0 + r) * ldc + col] = (f16)v;
      }
    }
  }
}

// ---------------------------------------------------------------------------
// Heads: mean = h12@Wm^T + bm ; log_std = clip(h22@Wls^T + bls, -20, 2). fp32 out.
// ---------------------------------------------------------------------------
__global__ __launch_bounds__(256) void head_kernel(
    const f16* __restrict__ H1, const f16* __restrict__ H2,
    const f16* __restrict__ Wm, const float* __restrict__ bm,
    const f16* __restrict__ Wls, const float* __restrict__ bls,
    float* __restrict__ OUT, int M, int K)
{
  const int tid = threadIdx.x, wid = tid >> 6, lane = tid & 63;
  const int m0 = blockIdx.x * 64 + wid * 16;
  const int kb = (lane >> 4) * 8, fr = lane & 15, fq = lane >> 4;

  f32x4 a1[2] = {}, a2[2] = {};
  for (int k0 = 0; k0 < K; k0 += 32) {
    f16x8 f1 = *(const f16x8*)&H1[(size_t)(m0 + fr) * K + k0 + kb];
    f16x8 f2 = *(const f16x8*)&H2[(size_t)(m0 + fr) * K + k0 + kb];
#pragma unroll
    for (int n = 0; n < 2; ++n) {
      f16x8 wm = *(const f16x8*)&Wm[(size_t)(n * 16 + fr) * K + k0 + kb];
      f16x8 wl = *(const f16x8*)&Wls[(size_t)(n * 16 + fr) * K + k0 + kb];
      a1[n] = MFMA16(f1, wm, a1[n]);
      a2[n] = MFMA16(f2, wl, a2[n]);
    }
  }

#pragma unroll
  for (int n = 0; n < 2; ++n) {
    const int col = n * 16 + fr;
    const float bvm = bm[col];
    const float bvl = bls[col];
#pragma unroll
    for (int r = 0; r < 4; ++r) {
      const int row = m0 + fq * 4 + r;
      OUT[(size_t)row * 32 + col] = a1[n][r] + bvm;
      float lv = a2[n][r] + bvl;
      OUT[(size_t)M * 32 + (size_t)row * 32 + col] = fminf(fmaxf(lv, -20.f), 2.f);
    }
  }
}

// ---------------------------------------------------------------------------
extern "C" void kernel_launch(void* const* d_in, const int* in_sizes, int n_in,
                              void* d_out, int out_size, void* d_ws, size_t ws_size,
                              hipStream_t stream) {
  const float* state = (const float*)d_in[0];
  const float* W_lif = (const float*)d_in[1];
  const float* b_lif = (const float*)d_in[2];
  const float* W11   = (const float*)d_in[3];
  const float* b11   = (const float*)d_in[4];
  const float* W12   = (const float*)d_in[5];
  const float* b12   = (const float*)d_in[6];
  const float* W21   = (const float*)d_in[7];
  const float* b21   = (const float*)d_in[8];
  const float* W22   = (const float*)d_in[9];
  const float* b22   = (const float*)d_in[10];
  const float* Wm    = (const float*)d_in[11];
  const float* bm    = (const float*)d_in[12];
  const float* Wls   = (const float*)d_in[13];
  const float* bls   = (const float*)d_in[14];
  float* out = (float*)d_out;

  const int B = 4096, IN = 512, H = 2048;
  char* ws = (char*)d_ws;
  // layout (bytes), peak 80.0 MB:
  f16* x    = (f16*)(ws);
  f16* h1   = (f16*)(ws + 16777216);
  f16* h2   = (f16*)(ws + 33554432);
  f16* s16  = (f16*)(ws + 50331648);
  f16* wl16 = (f16*)(ws + 71303168);
  f16* w4   = (f16*)(ws + 50331648);           // w11h|w21h|w12h|w22h contiguous
  f16* w11h = (f16*)(ws + 50331648);
  f16* w21h = (f16*)(ws + 58720256);
  f16* w12h = (f16*)(ws + 67108864);
  f16* w22h = (f16*)(ws + 75497472);
  f16* h22  = (f16*)(ws + 50331648);
  f16* wmh  = (f16*)(ws + 67108864);           // over w12h (dead after trunk2)
  f16* wlsh = (f16*)(ws + 67239936);
  f16* h12  = x;

  // 1) converts for LIF (state + W_lif in one dispatch)
  const int n8s = B * 5 * IN / 8, n8w = H * IN / 8;
  cvt2b_kernel<<<(n8s + n8w + 255) / 256, 256, 0, stream>>>(
      state, s16, n8s, W_lif, wl16, n8w);

  // 2) fused fc-GEMM + LIF -> x
  lif256_kernel<<<256, 512, 0, stream>>>(s16, wl16, b_lif, x);

  // 3) all four trunk weights -> contiguous fp16 (over s16, dead now)
  cvt4_kernel<<<4 * 524288 / 256, 256, 0, stream>>>(W11, W21, W12, W22, w4);

  // 4) trunk layer-1 (fused dual-output), then layer-2
  trunk256_kernel<<<256, 512, 0, stream>>>(x, x, H, w11h, w21h, b11, b21,
                                           h1, h2, H, 16, 8, H);
  trunk256_kernel<<<256, 512, 0, stream>>>(h1, h2, H, w12h, w22h, b12, b22,
                                           h12, h22, H, 16, 8, H);

  // 5) heads -> d_out = [mean | log_std] fp32
  cvt2_kernel<<<2 * (32 * H / 8) / 256, 256, 0, stream>>>(Wm, Wls, wmh, wlsh, 32 * H / 8);
  head_kernel<<<B / 64, 256, 0, stream>>>(h12, h22, wmh, bm, wlsh, bls, out, B, H);
}